// Round 1
// 487.055 us; speedup vs baseline: 1.0100x; 1.0100x over previous
//
#include <hip/hip_runtime.h>
#include <hip/hip_bf16.h>
#include <math.h>

// ---- problem constants ----
#define NH   16
#define HD   128
#define HID  2048
#define NKV  6144      // 3*NH*HD
#define B_   2
#define S_   2048
#define NC   32        // S/CHUNK
#define CHUNK_ 64
#define GROUPS_ 8

typedef __bf16 bf16_t;
typedef bf16_t bf16x8 __attribute__((ext_vector_type(8)));
typedef float  f32x4  __attribute__((ext_vector_type(4)));

__device__ __forceinline__ float b2f(unsigned int u) {
    union { unsigned int u; float f; } c; c.u = (u & 0xffffu) << 16; return c.f;
}
__device__ __forceinline__ unsigned int f2b(float f) {
    union { float f; unsigned int u; } c; c.f = f;
    unsigned int u = c.u;
    return (u + 0x7fffu + ((u >> 16) & 1u)) >> 16;
}

#define GLOAD_LDS16(gp, lp) __builtin_amdgcn_global_load_lds(                     \
    (const __attribute__((address_space(1))) void*)(gp),                          \
    (__attribute__((address_space(3))) void*)(lp), 16, 0, 0)

// ---------------- fp32 -> bf16 elementwise (8 elems/thread) ----------------
__global__ __launch_bounds__(256) void cvt_bf16(const float* __restrict__ in,
                                                unsigned short* __restrict__ out, int n8)
{
    int i = blockIdx.x * 256 + threadIdx.x;
    if (i >= n8) return;
    const float4* p = (const float4*)in + (size_t)i * 2;
    float4 a = p[0], b = p[1];
    uint4 o;
    o.x = f2b(a.x) | (f2b(a.y) << 16);
    o.y = f2b(a.z) | (f2b(a.w) << 16);
    o.z = f2b(b.x) | (f2b(b.y) << 16);
    o.w = f2b(b.z) | (f2b(b.w) << 16);
    ((uint4*)out)[i] = o;
}

// ------------- fp32 [K][N] -> bf16 [N][K] transpose (32x32 tiles) ---------------
__global__ __launch_bounds__(256) void transpose_cvt(const float* __restrict__ in,
                                                     unsigned short* __restrict__ out,
                                                     int Kdim, int Ndim)
{
    __shared__ float tile[32][33];
    int ntx = Ndim >> 5;
    int bx = blockIdx.x % ntx;
    int by = blockIdx.x / ntx;
    int lx = threadIdx.x & 31, ly = threadIdx.x >> 5;
    int r0 = by * 32, c0 = bx * 32;
    #pragma unroll
    for (int r = 0; r < 4; ++r)
        tile[ly + r * 8][lx] = in[(size_t)(r0 + ly + r * 8) * Ndim + c0 + lx];
    __syncthreads();
    #pragma unroll
    for (int r = 0; r < 4; ++r)
        out[(size_t)(c0 + ly + r * 8) * Kdim + r0 + lx] = (unsigned short)f2b(tile[lx][ly + r * 8]);
}

// ---------------- MFMA GEMM (plain): C[M,N] = A[M,K] @ Bt[N,K]^T ----------------
__device__ __forceinline__ void storeOne(float* p, float v) { *p = v; }
__device__ __forceinline__ void storeOne(unsigned short* p, float v) { *p = (unsigned short)f2b(v); }

template <typename OutT>
__global__ __launch_bounds__(256) void gemm_mfma(const bf16_t* __restrict__ A,   // [M][K]
                                                 const bf16_t* __restrict__ Bt,  // [N][K]
                                                 OutT* __restrict__ C,           // [M][N]
                                                 int M, int N, int K)
{
    __shared__ bf16_t As[128 * 32];
    __shared__ bf16_t Bs[128 * 32];
    int tid  = threadIdx.x;
    int ntiles = N >> 7;
    int bx = blockIdx.x % ntiles;
    int by = blockIdx.x / ntiles;
    int lane = tid & 63;
    int wave = tid >> 6;
    int wm = (wave >> 1) * 64;
    int wn = (wave & 1) * 64;
    int l16  = lane & 15;
    int quad = lane >> 4;

    f32x4 acc[4][4];
    #pragma unroll
    for (int i = 0; i < 4; ++i)
        #pragma unroll
        for (int j = 0; j < 4; ++j) { f32x4 z = {0.f, 0.f, 0.f, 0.f}; acc[i][j] = z; }

    const bf16_t* aG = A  + (size_t)(by * 128 + (tid >> 2)) * K + (tid & 3) * 8;
    const bf16_t* bG = Bt + (size_t)(bx * 128 + (tid >> 2)) * K + (tid & 3) * 8;
    bf16_t* aL0 = As + tid * 8;
    bf16_t* aL1 = As + 2048 + tid * 8;
    bf16_t* bL0 = Bs + tid * 8;
    bf16_t* bL1 = Bs + 2048 + tid * 8;
    const size_t half = (size_t)64 * K;

    for (int kt = 0; kt < K; kt += 32) {
        GLOAD_LDS16(aG + kt,        aL0);
        GLOAD_LDS16(aG + half + kt, aL1);
        GLOAD_LDS16(bG + kt,        bL0);
        GLOAD_LDS16(bG + half + kt, bL1);
        __syncthreads();
        bf16x8 af[4], bf[4];
        #pragma unroll
        for (int t = 0; t < 4; ++t) {
            af[t] = *(const bf16x8*)(As + (wm + t * 16 + l16) * 32 + quad * 8);
            bf[t] = *(const bf16x8*)(Bs + (wn + t * 16 + l16) * 32 + quad * 8);
        }
        #pragma unroll
        for (int mt = 0; mt < 4; ++mt)
            #pragma unroll
            for (int nt = 0; nt < 4; ++nt)
                acc[mt][nt] = __builtin_amdgcn_mfma_f32_16x16x32_bf16(af[mt], bf[nt], acc[mt][nt], 0, 0, 0);
        __syncthreads();
    }

    #pragma unroll
    for (int mt = 0; mt < 4; ++mt)
        #pragma unroll
        for (int nt = 0; nt < 4; ++nt) {
            int col = bx * 128 + wn + nt * 16 + l16;
            #pragma unroll
            for (int r = 0; r < 4; ++r) {
                int row = by * 128 + wm + mt * 16 + quad * 4 + r;
                storeOne(C + (size_t)row * N + col, acc[mt][nt][r]);
            }
        }
}

// ================= 256x256 8-phase GEMM (qkv+gate fused) =====================
// Template per learn_hip m201/m204: BM=BN=256, BK=64, 8 waves (2Mx4N), 512 thr,
// 128 KiB LDS (2 dbuf x 2 half x 128x64 x {A,B}), st_16x32 swizzle, counted
// vmcnt(6), setprio around each 16-MFMA quadrant cluster.
//
// Wave (wm,wn) owns rows {mh*128 + wm*64 .. +63} for mh in {0,1} and cols
// {nh*128 + wn*32 .. +31} for nh in {0,1}  -> each quadrant (mh,nh) touches
// exactly A-half mh / B-half nh, so half-tiles release one per phase and the
// prefetch of tile t+2 into the same buffer is always strictly after the last
// read of tile t's matching half (>=1 barrier in between; no WAR race).
//
// LDS layout per [buf][half]: 16 subtiles of 16 rows x 32 cols (1024 B each),
// subtile (R,C) at elem offset ((R*2+C)<<9); within-subtile elem offset
// (rr*32 + col) ^ ((rr>>3)&1)<<4  (st_16x32 swizzle). global_load_lds writes
// the subtile linearly (lane*16 B); the swizzle is folded into the per-lane
// GLOBAL source address (rule #21: linear dest + inverse-swz source + swz read).

__device__ __forceinline__ void ld_fr4(bf16x8 (&d)[4][2], const bf16_t* b, int s0, int ri) {
    #pragma unroll
    for (int i = 0; i < 4; ++i)
        #pragma unroll
        for (int k = 0; k < 2; ++k)
            d[i][k] = *(const bf16x8*)(b + (((s0 + i) * 2 + k) << 9) + ri);
}
__device__ __forceinline__ void ld_fr2(bf16x8 (&d)[2][2], const bf16_t* b, int s0, int ri) {
    #pragma unroll
    for (int i = 0; i < 2; ++i)
        #pragma unroll
        for (int k = 0; k < 2; ++k)
            d[i][k] = *(const bf16x8*)(b + (((s0 + i) * 2 + k) << 9) + ri);
}
__device__ __forceinline__ void mfma_quad(f32x4 (&a)[4][2], const bf16x8 (&af)[4][2],
                                          const bf16x8 (&bv)[2][2]) {
    #pragma unroll
    for (int mt = 0; mt < 4; ++mt)
        #pragma unroll
        for (int nt = 0; nt < 2; ++nt)
            #pragma unroll
            for (int ks = 0; ks < 2; ++ks)
                a[mt][nt] = __builtin_amdgcn_mfma_f32_16x16x32_bf16(af[mt][ks], bv[nt][ks], a[mt][nt], 0, 0, 0);
}

#define PH_PRE()  do { asm volatile("s_barrier" ::: "memory");                    \
                       asm volatile("s_waitcnt lgkmcnt(0)" ::: "memory");         \
                       __builtin_amdgcn_sched_barrier(0);                         \
                       __builtin_amdgcn_s_setprio(1); } while (0)
#define PH_POST() do { __builtin_amdgcn_s_setprio(0);                             \
                       asm volatile("s_barrier" ::: "memory"); } while (0)
#define VMCNT6()  asm volatile("s_waitcnt vmcnt(6)" ::: "memory")
#define VMCNT4()  asm volatile("s_waitcnt vmcnt(4)" ::: "memory")
#define VMCNT0()  asm volatile("s_waitcnt vmcnt(0)" ::: "memory")

__global__ __launch_bounds__(512, 2) void gemm_qg_256(const bf16_t* __restrict__ A,
                                                      const bf16_t* __restrict__ Bt,
                                                      unsigned short* __restrict__ Cq,
                                                      unsigned short* __restrict__ Cg)
{
    __shared__ bf16_t Asm[2][2][8192];   // [buf][half][128*64]
    __shared__ bf16_t Bsm[2][2][8192];
    const int K  = HID;       // 2048
    const int NT = K / 64;    // 32 K-tiles

    int tid  = threadIdx.x;
    int wave = tid >> 6, lane = tid & 63;
    int wm = wave >> 2, wn = wave & 3;            // 2 M-waves x 4 N-waves
    int l16 = lane & 15, quad = lane >> 4;
    int wm4 = wm * 4, wn2 = wn * 2;

    // XCD-aware swizzle (512 wg, 8 XCDs, 512%8==0 -> simple bijective form)
    int bid = blockIdx.x;
    int wg  = (bid & 7) * 64 + (bid >> 3);
    int bx  = wg & 31;        // 32 N-tiles (8192/256)
    int by  = wg >> 5;        // 16 M-tiles

    // swizzled within-subtile read offset (elems): row l16, col quad*8
    int rd_in = ((l16 << 5) | (quad << 3)) ^ (((l16 >> 3) & 1) << 4);

    // pre-swizzled global source decode for global_load_lds (one subtile/instr):
    // physical chunk = lane; logical chunk = lane ^ 2 for lane>=32
    int ch = lane ^ ((lane & 32) >> 4);
    int rr = ch >> 2;            // row within 16-row subtile
    int cc = (ch & 3) * 8;       // col (elems) within 32-col subtile

    // wave stages subtile row-block R=wave (C=0,1) of each half-tile
    const bf16_t* aSrc0 = A  + (size_t)(by * 256 +       wave * 16 + rr) * K + cc;
    const bf16_t* aSrc1 = A  + (size_t)(by * 256 + 128 + wave * 16 + rr) * K + cc;
    const bf16_t* bSrc0 = Bt + (size_t)(bx * 256 +       wave * 16 + rr) * K + cc;
    const bf16_t* bSrc1 = Bt + (size_t)(bx * 256 + 128 + wave * 16 + rr) * K + cc;

#define STAGE_A(h, t) do {                                                        \
        const bf16_t* _g = ((h) ? aSrc1 : aSrc0) + (size_t)(t) * 64;              \
        bf16_t* _l = &Asm[(t) & 1][(h)][wave * 1024 + lane * 8];                  \
        GLOAD_LDS16(_g,      _l);                                                 \
        GLOAD_LDS16(_g + 32, _l + 512); } while (0)
#define STAGE_B(h, t) do {                                                        \
        const bf16_t* _g = ((h) ? bSrc1 : bSrc0) + (size_t)(t) * 64;              \
        bf16_t* _l = &Bsm[(t) & 1][(h)][wave * 1024 + lane * 8];                  \
        GLOAD_LDS16(_g,      _l);                                                 \
        GLOAD_LDS16(_g + 32, _l + 512); } while (0)

    f32x4 acc[2][2][4][2];
    #pragma unroll
    for (int a0 = 0; a0 < 2; ++a0)
        #pragma unroll
        for (int a1 = 0; a1 < 2; ++a1)
            #pragma unroll
            for (int a2 = 0; a2 < 4; ++a2)
                #pragma unroll
                for (int a3 = 0; a3 < 2; ++a3) { f32x4 z = {0.f,0.f,0.f,0.f}; acc[a0][a1][a2][a3] = z; }
    bf16x8 af[4][2], bfv[2][2];

    // ---- prologue: tile 0 (4 halves), vmcnt(4), tile 1 (3 halves), vmcnt(6) ----
    STAGE_A(0, 0); STAGE_B(1, 0); STAGE_A(1, 0); STAGE_B(0, 0);
    VMCNT4();
    STAGE_A(0, 1); STAGE_B(1, 1); STAGE_A(1, 1);
    VMCNT6();
    asm volatile("s_barrier" ::: "memory");

    // ---- steady state: 4 phases/K-tile, quadrant order (0,0)(0,1)(1,1)(1,0) ----
    #pragma unroll 2
    for (int t = 0; t < NT - 2; ++t) {
        int buf = t & 1;
        // phase 0: quad (0,0)   reads A-h0 (8 ds) + B-h0 (4 ds)
        ld_fr4(af,  &Asm[buf][0][0], wm4, rd_in);
        ld_fr2(bfv, &Bsm[buf][0][0], wn2, rd_in);
        STAGE_B(0, t + 1);
        PH_PRE(); mfma_quad(acc[0][0], af, bfv); PH_POST();
        // phase 1: quad (0,1)   reads B-h1 (4 ds), A held
        ld_fr2(bfv, &Bsm[buf][1][0], wn2, rd_in);
        STAGE_A(0, t + 2);
        PH_PRE(); mfma_quad(acc[0][1], af, bfv); PH_POST();
        // phase 2: quad (1,1)   reads A-h1 (8 ds), B held
        ld_fr4(af,  &Asm[buf][1][0], wm4, rd_in);
        STAGE_B(1, t + 2);
        PH_PRE(); mfma_quad(acc[1][1], af, bfv); PH_POST();
        // phase 3: quad (1,0)   re-reads B-h0 (4 ds), A held
        ld_fr2(bfv, &Bsm[buf][0][0], wn2, rd_in);
        STAGE_A(1, t + 2);
        VMCNT6();   // 3 half-tiles (6 loads) stay in flight across the barrier
        PH_PRE(); mfma_quad(acc[1][0], af, bfv); PH_POST();
    }
    // ---- tail t = NT-2: stage only B-h0(NT-1); drain vmcnt before last tile ----
    {
        const int buf = (NT - 2) & 1;
        ld_fr4(af,  &Asm[buf][0][0], wm4, rd_in);
        ld_fr2(bfv, &Bsm[buf][0][0], wn2, rd_in);
        STAGE_B(0, NT - 1);
        PH_PRE(); mfma_quad(acc[0][0], af, bfv); PH_POST();
        ld_fr2(bfv, &Bsm[buf][1][0], wn2, rd_in);
        PH_PRE(); mfma_quad(acc[0][1], af, bfv); PH_POST();
        ld_fr4(af,  &Asm[buf][1][0], wm4, rd_in);
        PH_PRE(); mfma_quad(acc[1][1], af, bfv); PH_POST();
        ld_fr2(bfv, &Bsm[buf][0][0], wn2, rd_in);
        VMCNT0();
        PH_PRE(); mfma_quad(acc[1][0], af, bfv); PH_POST();
    }
    // ---- tail t = NT-1: pure compute ----
    {
        const int buf = (NT - 1) & 1;
        ld_fr4(af,  &Asm[buf][0][0], wm4, rd_in);
        ld_fr2(bfv, &Bsm[buf][0][0], wn2, rd_in);
        PH_PRE(); mfma_quad(acc[0][0], af, bfv); PH_POST();
        ld_fr2(bfv, &Bsm[buf][1][0], wn2, rd_in);
        PH_PRE(); mfma_quad(acc[0][1], af, bfv); PH_POST();
        ld_fr4(af,  &Asm[buf][1][0], wm4, rd_in);
        PH_PRE(); mfma_quad(acc[1][1], af, bfv); PH_POST();
        ld_fr2(bfv, &Bsm[buf][0][0], wn2, rd_in);
        PH_PRE(); mfma_quad(acc[1][0], af, bfv); PH_POST();
    }
#undef STAGE_A
#undef STAGE_B

    // ---- epilogue: route cols [0,6144)->Cq, [6144,8192)->Cg (256 | 6144) ----
    unsigned short* Cc; int Nn, colbase;
    if (bx < 24) { Cc = Cq; Nn = NKV; colbase = bx * 256; }
    else         { Cc = Cg; Nn = HID; colbase = bx * 256 - NKV; }
    int row0 = by * 256 + wm * 64 + quad * 4;
    int col0 = colbase + wn * 32 + l16;
    #pragma unroll
    for (int mh = 0; mh < 2; ++mh)
        #pragma unroll
        for (int nh = 0; nh < 2; ++nh)
            #pragma unroll
            for (int mt = 0; mt < 4; ++mt)
                #pragma unroll
                for (int nt = 0; nt < 2; ++nt) {
                    int col = col0 + nh * 128 + nt * 16;
                    #pragma unroll
                    for (int r = 0; r < 4; ++r) {
                        int row = row0 + mh * 128 + mt * 16 + r;
                        Cc[(size_t)row * Nn + col] = (unsigned short)f2b(acc[mh][nh][mt][nt][r]);
                    }
                }
}

// ------- q/k RMSNorm + partial RoPE, in place. grid = B*S blocks of 256. -------
__global__ __launch_bounds__(256) void norm_rope(unsigned short* __restrict__ qkv,
                                                 const int* __restrict__ positions,
                                                 const float* __restrict__ qw,
                                                 const float* __restrict__ kw)
{
    int bs = blockIdx.x;
    int s  = bs & (S_ - 1);
    int tid = threadIdx.x;
    int l16 = tid & 15;
    unsigned short* base = qkv + (size_t)bs * NKV;
    float pos = (float)positions[s];

    #pragma unroll
    for (int p = 0; p < 2; ++p) {
        int rr = p * 16 + (tid >> 4);   // 0..31
        int qk = rr >> 4;
        int h  = rr & 15;
        unsigned short* row = base + qk * HID + h * HD;
        const float* w = qk ? kw : qw;
        uint4 v = *(const uint4*)(row + l16 * 8);
        float x[8];
        x[0] = b2f(v.x); x[1] = b2f(v.x >> 16);
        x[2] = b2f(v.y); x[3] = b2f(v.y >> 16);
        x[4] = b2f(v.z); x[5] = b2f(v.z >> 16);
        x[6] = b2f(v.w); x[7] = b2f(v.w >> 16);
        float ss = 0.f;
        #pragma unroll
        for (int t = 0; t < 8; ++t) ss += x[t] * x[t];
        ss += __shfl_xor(ss, 1); ss += __shfl_xor(ss, 2);
        ss += __shfl_xor(ss, 4); ss += __shfl_xor(ss, 8);
        float inv = rsqrtf(ss * (1.0f / 128.0f) + 1e-6f);
        float n[8];
        #pragma unroll
        for (int t = 0; t < 8; ++t) n[t] = x[t] * inv * w[l16 * 8 + t];
        float pr[8];
        #pragma unroll
        for (int t = 0; t < 8; ++t) pr[t] = __shfl_xor(n[t], 4);   // dims +-32
        if (l16 < 8) {
            #pragma unroll
            for (int t = 0; t < 8; ++t) {
                int dim = l16 * 8 + t;
                int i = dim & 31;
                float ang = pos * exp2f(-(float)i * 0.4152410118609203f);
                float cs = cosf(ang), sn = sinf(ang);
                n[t] = (dim < 32) ? (n[t] * cs - pr[t] * sn) : (n[t] * cs + pr[t] * sn);
            }
        }
        uint4 o;
        o.x = f2b(n[0]) | (f2b(n[1]) << 16);
        o.y = f2b(n[2]) | (f2b(n[3]) << 16);
        o.z = f2b(n[4]) | (f2b(n[5]) << 16);
        o.w = f2b(n[6]) | (f2b(n[7]) << 16);
        *(uint4*)(row + l16 * 8) = o;
    }
}

// ============ pass 1: per-chunk KV outer product  Wt[e][d] = sum_j kdec_j V[j][e] K[j][d]
__global__ __launch_bounds__(256) void chunk_kv(const unsigned short* __restrict__ qkv,
                                                unsigned short* __restrict__ wbuf)
{
    __shared__ unsigned short kt[128 * 72];   // kt[d][j]
    __shared__ unsigned short vt[128 * 72];   // vt[e][j] * kdec[j]
    int bi = blockIdx.x;
    int c = bi & 31, bh = bi >> 5, h = bh & 15, b = bh >> 4;
    int tid = threadIdx.x;
    float slope = -exp2f(-0.5f * (float)(h + 1)) * (1.0f + 1e-5f);

    const unsigned short* kbase = qkv + ((size_t)(b * S_ + c * CHUNK_)) * NKV + HID + h * HD;
    const unsigned short* vbase = kbase + HID;

    for (int idx = tid; idx < 4096; idx += 256) {
        int j = idx >> 6, p = idx & 63;
        unsigned int ku = *(const unsigned int*)(kbase + (size_t)j * NKV + p * 2);
        kt[(2 * p) * 72 + j]     = (unsigned short)(ku & 0xffffu);
        kt[(2 * p + 1) * 72 + j] = (unsigned short)(ku >> 16);
        float kd = expf(slope * (float)(63 - j));
        unsigned int vu = *(const unsigned int*)(vbase + (size_t)j * NKV + p * 2);
        vt[(2 * p) * 72 + j]     = (unsigned short)f2b(b2f(vu) * kd);
        vt[(2 * p + 1) * 72 + j] = (unsigned short)f2b(b2f(vu >> 16) * kd);
    }
    __syncthreads();

    int lane = tid & 63, wave = tid >> 6;
    int wm = (wave >> 1) * 64;     // e
    int wn = (wave & 1) * 64;      // d
    int l16 = lane & 15, quad = lane >> 4;

    f32x4 acc[4][4];
    #pragma unroll
    for (int i = 0; i < 4; ++i)
        #pragma unroll
        for (int j = 0; j < 4; ++j) { f32x4 z = {0.f,0.f,0.f,0.f}; acc[i][j] = z; }

    #pragma unroll
    for (int ks = 0; ks < 64; ks += 32) {
        bf16x8 af[4], bf[4];
        #pragma unroll
        for (int t = 0; t < 4; ++t) {
            af[t] = *(const bf16x8*)((const bf16_t*)vt + (wm + t * 16 + l16) * 72 + ks + quad * 8);
            bf[t] = *(const bf16x8*)((const bf16_t*)kt + (wn + t * 16 + l16) * 72 + ks + quad * 8);
        }
        #pragma unroll
        for (int mt = 0; mt < 4; ++mt)
            #pragma unroll
            for (int nt = 0; nt < 4; ++nt)
                acc[mt][nt] = __builtin_amdgcn_mfma_f32_16x16x32_bf16(af[mt], bf[nt], acc[mt][nt], 0, 0, 0);
    }

    unsigned short* wp = wbuf + ((size_t)bi << 14);  // [e][d] 128x128
    #pragma unroll
    for (int mt = 0; mt < 4; ++mt)
        #pragma unroll
        for (int nt = 0; nt < 4; ++nt) {
            int dcol = wn + nt * 16 + l16;
            #pragma unroll
            for (int r = 0; r < 4; ++r) {
                int erow = wm + mt * 16 + quad * 4 + r;
                wp[(size_t)erow * 128 + dcol] = (unsigned short)f2b(acc[mt][nt][r]);
            }
        }
}

// ============ pass 2: sequential state scan (linear recurrence), 512 blocks
__global__ __launch_bounds__(256) void state_scan(const unsigned short* __restrict__ wbuf,
                                                  const float* __restrict__ rs0,
                                                  unsigned short* __restrict__ stbuf)
{
    int bi = blockIdx.x;
    int es = bi & 15, bh = bi >> 4, h = bh & 15, b = bh >> 4;
    int tid = threadIdx.x;
    float slope = -exp2f(-0.5f * (float)(h + 1)) * (1.0f + 1e-5f);
    float lam = expf(slope * 64.0f);

    int e  = es * 8 + (tid >> 5);
    int d0 = (tid & 31) * 4;

    float S[4];
    const float* rp = rs0 + ((size_t)(b * NH + h)) * HD * HD + e;   // rstate[b][h][d][e]
    #pragma unroll
    for (int t = 0; t < 4; ++t) S[t] = rp[(size_t)(d0 + t) * HD];

    size_t off = (size_t)e * 128 + d0;
    for (int c = 0; c < NC; ++c) {
        size_t base = (((size_t)bh * NC + c) << 14) + off;
        uint2 o;
        o.x = f2b(S[0]) | (f2b(S[1]) << 16);
        o.y = f2b(S[2]) | (f2b(S[3]) << 16);
        *(uint2*)(stbuf + base) = o;
        uint2 w = *(const uint2*)(wbuf + base);
        S[0] = S[0] * lam + b2f(w.x);
        S[1] = S[1] * lam + b2f(w.x >> 16);
        S[2] = S[2] * lam + b2f(w.y);
        S[3] = S[3] * lam + b2f(w.y >> 16);
    }
}

// ============ pass 3: per-chunk output  O = (mask.QK^T)@V + qdec*(Q@S_prev)
__global__ __launch_bounds__(256) void chunk_out(const unsigned short* __restrict__ qkv,
                                                 const unsigned short* __restrict__ stbuf,
                                                 unsigned short* __restrict__ obuf)
{
    __shared__ unsigned short qs[64 * 136];   // q[i][d]
    __shared__ unsigned short vt[128 * 72];   // v^T[e][j]
    __shared__ unsigned short sc[64 * 72];    // masked scores [i][j]

    int bi = blockIdx.x;
    int c = bi & 31, bh = bi >> 5, h = bh & 15, b = bh >> 4;
    int tid = threadIdx.x;
    float slope = -exp2f(-0.5f * (float)(h + 1)) * (1.0f + 1e-5f);

    int lane = tid & 63, wave = tid >> 6;
    int l16 = lane & 15, quad = lane >> 4;
    int wn3 = wave * 32;

    // ---- prefetch st B-frags into registers FIRST: HBM latency (~900cyc) hides
    //      behind staging + scores + intra phases.
    const unsigned short* stp = stbuf + (((size_t)bh * NC + c) << 14);
    bf16x8 bsf[4][2];
    #pragma unroll
    for (int ksp4 = 0; ksp4 < 4; ++ksp4)
        #pragma unroll
        for (int nt = 0; nt < 2; ++nt)
            bsf[ksp4][nt] = *(const bf16x8*)((const bf16_t*)stp +
                (size_t)(wn3 + nt * 16 + l16) * 128 + ksp4 * 32 + quad * 8);

    const unsigned short* qrow = qkv + ((size_t)(b * S_ + c * CHUNK_)) * NKV + h * HD;
    const unsigned short* krow = qrow + HID;
    // stage q (rows of 128, padded stride 136)
    for (int idx = tid; idx < 1024; idx += 256) {
        int row = idx >> 4, c8 = (idx & 15) * 8;
        *(uint4*)(qs + row * 136 + c8) = *(const uint4*)(qrow + (size_t)row * NKV + c8);
    }
    // stage v transposed
    const unsigned short* vbase = qrow + 2 * HID;
    for (int idx = tid; idx < 4096; idx += 256) {
        int j = idx >> 6, p = idx & 63;
        unsigned int vu = *(const unsigned int*)(vbase + (size_t)j * NKV + p * 2);
        vt[(2 * p) * 72 + j]     = (unsigned short)(vu & 0xffffu);
        vt[(2 * p + 1) * 72 + j] = (unsigned short)(vu >> 16);
    }
    __syncthreads();

    // ---- scores: each wave computes rows [wave*16, +16) x all 64 j; k-frags global ----
    {
        f32x4 accS[4];
        #pragma unroll
        for (int t = 0; t < 4; ++t) { f32x4 z = {0.f,0.f,0.f,0.f}; accS[t] = z; }
        #pragma unroll
        for (int ksp = 0; ksp < 128; ksp += 32) {
            bf16x8 aq = *(const bf16x8*)((const bf16_t*)qs + (wave * 16 + l16) * 136 + ksp + quad * 8);
            #pragma unroll
            for (int nt = 0; nt < 4; ++nt) {
                bf16x8 bk = *(const bf16x8*)((const bf16_t*)krow + (size_t)(nt * 16 + l16) * NKV + ksp + quad * 8);
                accS[nt] = __builtin_amdgcn_mfma_f32_16x16x32_bf16(aq, bk, accS[nt], 0, 0, 0);
            }
        }
        float ad[4];
        #pragma unroll
        for (int r = 0; r < 4; ++r) ad[r] = expf(slope * (float)(wave * 16 + quad * 4 + r));
        #pragma unroll
        for (int nt = 0; nt < 4; ++nt) {
            int j = nt * 16 + l16;
            float bd = expf(-slope * (float)j);
            #pragma unroll
            for (int r = 0; r < 4; ++r) {
                int i = wave * 16 + quad * 4 + r;
                float v = (i >= j) ? accS[nt][r] * ad[r] * bd : 0.0f;
                sc[i * 72 + j] = (unsigned short)f2b(v);
            }
        }
    }
    __syncthreads();

    f32x4 accI[4][2], accE[4][2];
    #pragma unroll
    for (int i = 0; i < 4; ++i)
        #pragma unroll
        for (int j = 0; j < 2; ++j) { f32x4 z = {0.f,0.f,0.f,0.f}; accI[i][j] = z; accE[i][j] = z; }

    // intra: K = 64 (j)
    #pragma unroll
    for (int ksp = 0; ksp < 64; ksp += 32) {
        bf16x8 as[4], bv[2];
        #pragma unroll
        for (int mt = 0; mt < 4; ++mt)
            as[mt] = *(const bf16x8*)((const bf16_t*)sc + (mt * 16 + l16) * 72 + ksp + quad * 8);
        #pragma unroll
        for (int nt = 0; nt < 2; ++nt)
            bv[nt] = *(const bf16x8*)((const bf16_t*)vt + (wn3 + nt * 16 + l16) * 72 + ksp + quad * 8);
        #pragma unroll
        for (int mt = 0; mt < 4; ++mt)
            #pragma unroll
            for (int nt = 0; nt < 2; ++nt)
                accI[mt][nt] = __builtin_amdgcn_mfma_f32_16x16x32_bf16(as[mt], bv[nt], accI[mt][nt], 0, 0, 0);
    }
    // inter: K = 128 (d), B-frags already in registers (bsf)
    #pragma unroll
    for (int ksp4 = 0; ksp4 < 4; ++ksp4) {
        bf16x8 aq[4];
        #pragma unroll
        for (int mt = 0; mt < 4; ++mt)
            aq[mt] = *(const bf16x8*)((const bf16_t*)qs + (mt * 16 + l16) * 136 + ksp4 * 32 + quad * 8);
        #pragma unroll
        for (int mt = 0; mt < 4; ++mt)
            #pragma unroll
            for (int nt = 0; nt < 2; ++nt)
                accE[mt][nt] = __builtin_amdgcn_mfma_f32_16x16x32_bf16(aq[mt], bsf[ksp4][nt], accE[mt][nt], 0, 0, 0);
    }

    // epilogue: O = accI + qdec[i]*accE, bf16 store
    #pragma unroll
    for (int mt = 0; mt < 4; ++mt) {
        #pragma unroll
        for (int r = 0; r < 4; ++r) {
            int i = mt * 16 + quad * 4 + r;
            float qd = expf(slope * (float)(i + 1));
            int orow = b * S_ + c * CHUNK_ + i;
            #pragma unroll
            for (int nt = 0; nt < 2; ++nt) {
                int col = h * HD + wn3 + nt * 16 + l16;
                float o = accI[mt][nt][r] + qd * accE[mt][nt][r];
                obuf[(size_t)orow * 2048 + col] = (unsigned short)f2b(o);
            }
        }
    }
}

// ------- group RMSNorm + sigmoid gate: read o bf16 + gate bf16, write bf16 -------
__global__ __launch_bounds__(256) void gnorm_gate(const unsigned short* __restrict__ o,
                                                  unsigned short* __restrict__ gate,
                                                  const float* __restrict__ gw)
{
    int row = blockIdx.x >> 3;
    int g   = blockIdx.x & 7;
    int col = g * 256 + threadIdx.x;
    size_t idx = (size_t)row * 2048 + col;
    float ov = b2f(o[idx]);
    float ss = ov * ov;
    #pragma unroll
    for (int off = 32; off > 0; off >>= 1) ss += __shfl_xor(ss, off);
    __shared__ float part[4];
    if ((threadIdx.x & 63) == 0) part[threadIdx.x >> 6] = ss;
    __syncthreads();
    float tot = part[0] + part[1] + part[2] + part[3];
    float inv = rsqrtf(tot * (1.0f / 256.0f) + 1e-6f);
    float gv = b2f(gate[idx]);
    float sig = 1.0f / (1.0f + expf(-gv));
    gate[idx] = (unsigned short)f2b(ov * inv * gw[col] * sig);
}

// ---------------- launch ----------------
extern "C" void kernel_launch(void* const* d_in, const int* in_sizes, int n_in,
                              void* d_out, int out_size, void* d_ws, size_t ws_size,
                              hipStream_t stream) {
    const int*   positions = (const int*)d_in[0];
    const float* hidden    = (const float*)d_in[1];
    const float* rstate    = (const float*)d_in[2];
    const float* w_qkv     = (const float*)d_in[3];
    const float* w_g       = (const float*)d_in[4];
    const float* w_dense   = (const float*)d_in[5];
    const float* q_norm_w  = (const float*)d_in[6];
    const float* k_norm_w  = (const float*)d_in[7];
    const float* g_norm_w  = (const float*)d_in[8];
    float* out = (float*)d_out;

    const int MR = B_ * S_;  // 4096

    // ---- ws layout (total 159,383,552 B — unchanged) ----
    char* w = (char*)d_ws;
    unsigned short* qkv  = (unsigned short*)w;            w += (size_t)MR * NKV * 2;     // 50.3 MB
    unsigned short* gbuf = (unsigned short*)w;            w += (size_t)MR * 2048 * 2;    // 16.8 MB
    unsigned short* wdT  = (unsigned short*)w;            w += (size_t)HID * HID * 2;    // 8.4 MB
    char* regionA = w;                                    w += (size_t)MR * HID * 2 + (size_t)8192 * HID * 2; // 50.3 MB
    char* regionB = w;                                    // 33.6 MB
    unsigned short* hbf   = (unsigned short*)regionA;                                 // 16.8 MB
    unsigned short* btQG  = (unsigned short*)(regionA + (size_t)MR * HID * 2);        // [8192][2048] 33.5 MB
    unsigned short* wqT   = btQG;                                                     // rows 0..6143
    unsigned short* wgT   = btQG + (size_t)NKV * HID;                                 // rows 6144..8191
    unsigned short* stbuf = (unsigned short*)regionA;     // 32 MB, after GEMMs
    unsigned short* wbuf  = (unsigned short*)regionB;     // 32 MB
    unsigned short* obuf  = (unsigned short*)regionB;     // 16.8 MB, after pass2

    // ---- conversions ----
    cvt_bf16<<<dim3((MR * HID / 8 + 255) / 256), dim3(256), 0, stream>>>(hidden, hbf, MR * HID / 8);
    transpose_cvt<<<dim3((HID / 32) * (NKV / 32)), dim3(256), 0, stream>>>(w_qkv, wqT, HID, NKV);
    transpose_cvt<<<dim3((HID / 32) * (HID / 32)), dim3(256), 0, stream>>>(w_g, wgT, HID, HID);
    transpose_cvt<<<dim3((HID / 32) * (HID / 32)), dim3(256), 0, stream>>>(w_dense, wdT, HID, HID);

    // ---- fused qkv+gate projection: 256^2 8-phase (512 wg x 512 thr) ----
    gemm_qg_256<<<dim3(512), dim3(512), 0, stream>>>(
        (const bf16_t*)hbf, (const bf16_t*)btQG, qkv, gbuf);
    // ---- q/k norm + rope (in place) ----
    norm_rope<<<dim3(B_ * S_), dim3(256), 0, stream>>>(qkv, positions, q_norm_w, k_norm_w);

    // ---- attention: 3-pass chunked scan ----
    chunk_kv<<<dim3(B_ * NH * NC), dim3(256), 0, stream>>>(qkv, wbuf);
    state_scan<<<dim3(B_ * NH * 16), dim3(256), 0, stream>>>(wbuf, rstate, stbuf);
    chunk_out<<<dim3(B_ * NH * NC), dim3(256), 0, stream>>>(qkv, stbuf, obuf);

    // ---- group norm + gate ----
    gnorm_gate<<<dim3(MR * GROUPS_), dim3(256), 0, stream>>>(obuf, gbuf, g_norm_w);
    // ---- output projection (fp32 out) ----
    gemm_mfma<float><<<dim3((MR / 128) * (HID / 128)), dim3(256), 0, stream>>>(
        (const bf16_t*)gbuf, (const bf16_t*)wdT, out, MR, HID, HID);
}

// Round 2
// 464.740 us; speedup vs baseline: 1.0585x; 1.0480x over previous
//
#include <hip/hip_runtime.h>
#include <hip/hip_bf16.h>
#include <math.h>

// ---- problem constants ----
#define NH   16
#define HD   128
#define HID  2048
#define NKV  6144      // 3*NH*HD
#define B_   2
#define S_   2048
#define NC   32        // S/CHUNK
#define CHUNK_ 64
#define GROUPS_ 8

typedef __bf16 bf16_t;
typedef bf16_t bf16x8 __attribute__((ext_vector_type(8)));
typedef float  f32x4  __attribute__((ext_vector_type(4)));

__device__ __forceinline__ float b2f(unsigned int u) {
    union { unsigned int u; float f; } c; c.u = (u & 0xffffu) << 16; return c.f;
}
__device__ __forceinline__ unsigned int f2b(float f) {
    union { float f; unsigned int u; } c; c.f = f;
    unsigned int u = c.u;
    return (u + 0x7fffu + ((u >> 16) & 1u)) >> 16;
}

#define GLOAD_LDS16(gp, lp) __builtin_amdgcn_global_load_lds(                     \
    (const __attribute__((address_space(1))) void*)(gp),                          \
    (__attribute__((address_space(3))) void*)(lp), 16, 0, 0)

// ---------------- fp32 -> bf16 elementwise (8 elems/thread) ----------------
__global__ __launch_bounds__(256) void cvt_bf16(const float* __restrict__ in,
                                                unsigned short* __restrict__ out, int n8)
{
    int i = blockIdx.x * 256 + threadIdx.x;
    if (i >= n8) return;
    const float4* p = (const float4*)in + (size_t)i * 2;
    float4 a = p[0], b = p[1];
    uint4 o;
    o.x = f2b(a.x) | (f2b(a.y) << 16);
    o.y = f2b(a.z) | (f2b(a.w) << 16);
    o.z = f2b(b.x) | (f2b(b.y) << 16);
    o.w = f2b(b.z) | (f2b(b.w) << 16);
    ((uint4*)out)[i] = o;
}

// ------------- fp32 [K][N] -> bf16 [N][K] transpose (32x32 tiles) ---------------
__global__ __launch_bounds__(256) void transpose_cvt(const float* __restrict__ in,
                                                     unsigned short* __restrict__ out,
                                                     int Kdim, int Ndim)
{
    __shared__ float tile[32][33];
    int ntx = Ndim >> 5;
    int bx = blockIdx.x % ntx;
    int by = blockIdx.x / ntx;
    int lx = threadIdx.x & 31, ly = threadIdx.x >> 5;
    int r0 = by * 32, c0 = bx * 32;
    #pragma unroll
    for (int r = 0; r < 4; ++r)
        tile[ly + r * 8][lx] = in[(size_t)(r0 + ly + r * 8) * Ndim + c0 + lx];
    __syncthreads();
    #pragma unroll
    for (int r = 0; r < 4; ++r)
        out[(size_t)(c0 + ly + r * 8) * Kdim + r0 + lx] = (unsigned short)f2b(tile[lx][ly + r * 8]);
}

// ---------------- MFMA GEMM (plain): C[M,N] = A[M,K] @ Bt[N,K]^T ----------------
__device__ __forceinline__ void storeOne(float* p, float v) { *p = v; }
__device__ __forceinline__ void storeOne(unsigned short* p, float v) { *p = (unsigned short)f2b(v); }

template <typename OutT>
__global__ __launch_bounds__(256) void gemm_mfma(const bf16_t* __restrict__ A,   // [M][K]
                                                 const bf16_t* __restrict__ Bt,  // [N][K]
                                                 OutT* __restrict__ C,           // [M][N]
                                                 int M, int N, int K)
{
    __shared__ bf16_t As[128 * 32];
    __shared__ bf16_t Bs[128 * 32];
    int tid  = threadIdx.x;
    int ntiles = N >> 7;
    int bx = blockIdx.x % ntiles;
    int by = blockIdx.x / ntiles;
    int lane = tid & 63;
    int wave = tid >> 6;
    int wm = (wave >> 1) * 64;
    int wn = (wave & 1) * 64;
    int l16  = lane & 15;
    int quad = lane >> 4;

    f32x4 acc[4][4];
    #pragma unroll
    for (int i = 0; i < 4; ++i)
        #pragma unroll
        for (int j = 0; j < 4; ++j) { f32x4 z = {0.f, 0.f, 0.f, 0.f}; acc[i][j] = z; }

    const bf16_t* aG = A  + (size_t)(by * 128 + (tid >> 2)) * K + (tid & 3) * 8;
    const bf16_t* bG = Bt + (size_t)(bx * 128 + (tid >> 2)) * K + (tid & 3) * 8;
    bf16_t* aL0 = As + tid * 8;
    bf16_t* aL1 = As + 2048 + tid * 8;
    bf16_t* bL0 = Bs + tid * 8;
    bf16_t* bL1 = Bs + 2048 + tid * 8;
    const size_t half = (size_t)64 * K;

    for (int kt = 0; kt < K; kt += 32) {
        GLOAD_LDS16(aG + kt,        aL0);
        GLOAD_LDS16(aG + half + kt, aL1);
        GLOAD_LDS16(bG + kt,        bL0);
        GLOAD_LDS16(bG + half + kt, bL1);
        __syncthreads();
        bf16x8 af[4], bf[4];
        #pragma unroll
        for (int t = 0; t < 4; ++t) {
            af[t] = *(const bf16x8*)(As + (wm + t * 16 + l16) * 32 + quad * 8);
            bf[t] = *(const bf16x8*)(Bs + (wn + t * 16 + l16) * 32 + quad * 8);
        }
        #pragma unroll
        for (int mt = 0; mt < 4; ++mt)
            #pragma unroll
            for (int nt = 0; nt < 4; ++nt)
                acc[mt][nt] = __builtin_amdgcn_mfma_f32_16x16x32_bf16(af[mt], bf[nt], acc[mt][nt], 0, 0, 0);
        __syncthreads();
    }

    #pragma unroll
    for (int mt = 0; mt < 4; ++mt)
        #pragma unroll
        for (int nt = 0; nt < 4; ++nt) {
            int col = bx * 128 + wn + nt * 16 + l16;
            #pragma unroll
            for (int r = 0; r < 4; ++r) {
                int row = by * 128 + wm + mt * 16 + quad * 4 + r;
                storeOne(C + (size_t)row * N + col, acc[mt][nt][r]);
            }
        }
}

// ================= 256x256 8-phase GEMM (qkv+gate fused) =====================
// v2: early-issue ds_reads + compiler counted-lgkm (no forced lgkmcnt(0)).
// Round-1 postmortem: in-phase reads + lgkmcnt(0) serialized LDS service
// (2.7Kcyc/CU/Ktile) against MFMA (2.5Kcyc) -> MfmaUtil 35%. Now each
// quadrant's reads are issued >=1 phase before use so the LDS unit services
// them under the previous MFMA cluster; compiler emits counted lgkmcnt(N)
// before each dependent MFMA (IR-visible loads).
//
// Per K-tile (quadrant order (0,0)(0,1)(1,1)(1,0); A0 in afA, A1 in afB,
// B halves both held -> 24 reads/wave/K-tile):
//  p0: [stage B0(t+1)]                 MFMA(0,0) afA,bf0
//  p1: [ld afB<-A1 | stage A0(t+2)]    MFMA(0,1) afA,bf1   (A1 drains here)
//  p2: [stage B1(t+2)]                 MFMA(1,1) afB,bf1   (LDS catch-up)
//  p3: [stage A1(t+2); vmcnt(6); bar;
//       ld afA<-A0[nbuf], bf1<-B1[nbuf]] MFMA(1,0) afB,bf0 (12 rds drain here)
//      [ld bf0<-B0[nbuf]]              (4-read tail, drains in p0 body)
// Safety: tile t+1 frag reads sit after p3's vmcnt(6)+barrier, which completes
// all stages through SB0(t+1) CU-wide (issue order A0,B1,A1 @t-1 + B0 @p0(t)).

__device__ __forceinline__ void ld_fr4(bf16x8 (&d)[4][2], const bf16_t* b, int s0, int ri) {
    #pragma unroll
    for (int i = 0; i < 4; ++i)
        #pragma unroll
        for (int k = 0; k < 2; ++k)
            d[i][k] = *(const bf16x8*)(b + (((s0 + i) * 2 + k) << 9) + ri);
}
__device__ __forceinline__ void ld_fr2(bf16x8 (&d)[2][2], const bf16_t* b, int s0, int ri) {
    #pragma unroll
    for (int i = 0; i < 2; ++i)
        #pragma unroll
        for (int k = 0; k < 2; ++k)
            d[i][k] = *(const bf16x8*)(b + (((s0 + i) * 2 + k) << 9) + ri);
}
__device__ __forceinline__ void mfma_quad(f32x4 (&a)[4][2], const bf16x8 (&af)[4][2],
                                          const bf16x8 (&bv)[2][2]) {
    #pragma unroll
    for (int mt = 0; mt < 4; ++mt)
        #pragma unroll
        for (int nt = 0; nt < 2; ++nt)
            #pragma unroll
            for (int ks = 0; ks < 2; ++ks)
                a[mt][nt] = __builtin_amdgcn_mfma_f32_16x16x32_bf16(af[mt][ks], bv[nt][ks], a[mt][nt], 0, 0, 0);
}

#define BAR()     asm volatile("s_barrier" ::: "memory")
#define PRIO1()   __builtin_amdgcn_s_setprio(1)
#define PRIO0()   __builtin_amdgcn_s_setprio(0)
#define SCHEDB()  __builtin_amdgcn_sched_barrier(0)
#define VMCNT6()  asm volatile("s_waitcnt vmcnt(6)" ::: "memory")
#define VMCNT0()  asm volatile("s_waitcnt vmcnt(0)" ::: "memory")

__global__ __launch_bounds__(512, 2) void gemm_qg_256(const bf16_t* __restrict__ A,
                                                      const bf16_t* __restrict__ Bt,
                                                      unsigned short* __restrict__ Cq,
                                                      unsigned short* __restrict__ Cg)
{
    __shared__ bf16_t Asm[2][2][8192];   // [buf][half][128*64]
    __shared__ bf16_t Bsm[2][2][8192];
    const int K  = HID;       // 2048
    const int NT = K / 64;    // 32 K-tiles

    int tid  = threadIdx.x;
    int wave = tid >> 6, lane = tid & 63;
    int wm = wave >> 2, wn = wave & 3;            // 2 M-waves x 4 N-waves
    int l16 = lane & 15, quad = lane >> 4;
    int wm4 = wm * 4, wn2 = wn * 2;

    // XCD-aware mapping: each XCD (bid&7) owns an 8x8 (by,bx) tile block ->
    // ~8.4MB A + 8.4MB B per XCD (was 2 row-panels x all cols = 33.5MB B/XCD,
    // measured 270MB fetch). 512 = 8*64 exact -> bijective.
    int bid = blockIdx.x;
    int xcd = bid & 7, idx = bid >> 3;            // idx in 0..63
    int by  = (xcd >> 2) * 8 + (idx >> 3);        // 0..15
    int bx  = (xcd & 3) * 8 + (idx & 7);          // 0..31

    // swizzled within-subtile read offset (elems): row l16, col quad*8
    int rd_in = ((l16 << 5) | (quad << 3)) ^ (((l16 >> 3) & 1) << 4);

    // pre-swizzled global source decode for global_load_lds (one subtile/instr)
    int ch = lane ^ ((lane & 32) >> 4);
    int rr = ch >> 2;            // row within 16-row subtile
    int cc = (ch & 3) * 8;       // col (elems) within 32-col subtile

    // wave stages subtile row-block R=wave (C=0,1) of each half-tile
    const bf16_t* aSrc0 = A  + (size_t)(by * 256 +       wave * 16 + rr) * K + cc;
    const bf16_t* aSrc1 = A  + (size_t)(by * 256 + 128 + wave * 16 + rr) * K + cc;
    const bf16_t* bSrc0 = Bt + (size_t)(bx * 256 +       wave * 16 + rr) * K + cc;
    const bf16_t* bSrc1 = Bt + (size_t)(bx * 256 + 128 + wave * 16 + rr) * K + cc;

#define STAGE_A(h, t) do {                                                        \
        const bf16_t* _g = ((h) ? aSrc1 : aSrc0) + (size_t)(t) * 64;              \
        bf16_t* _l = &Asm[(t) & 1][(h)][wave * 1024 + lane * 8];                  \
        GLOAD_LDS16(_g,      _l);                                                 \
        GLOAD_LDS16(_g + 32, _l + 512); } while (0)
#define STAGE_B(h, t) do {                                                        \
        const bf16_t* _g = ((h) ? bSrc1 : bSrc0) + (size_t)(t) * 64;              \
        bf16_t* _l = &Bsm[(t) & 1][(h)][wave * 1024 + lane * 8];                  \
        GLOAD_LDS16(_g,      _l);                                                 \
        GLOAD_LDS16(_g + 32, _l + 512); } while (0)

    f32x4 acc[2][2][4][2];
    #pragma unroll
    for (int a0 = 0; a0 < 2; ++a0)
        #pragma unroll
        for (int a1 = 0; a1 < 2; ++a1)
            #pragma unroll
            for (int a2 = 0; a2 < 4; ++a2)
                #pragma unroll
                for (int a3 = 0; a3 < 2; ++a3) { f32x4 z = {0.f,0.f,0.f,0.f}; acc[a0][a1][a2][a3] = z; }

    bf16x8 afA[4][2], afB[4][2];   // A-h0, A-h1 frags
    bf16x8 bf0[2][2], bf1[2][2];   // B-h0, B-h1 frags

    // ---- prologue: tile0 (4 halves) + tile1 {A0,B1,A1}; vmcnt(6) leaves the
    //      3 tile-1 stages in flight (steady-state invariant); then tile-0 frags.
    STAGE_A(0, 0); STAGE_B(0, 0); STAGE_B(1, 0); STAGE_A(1, 0);
    STAGE_A(0, 1); STAGE_B(1, 1); STAGE_A(1, 1);
    VMCNT6();
    BAR();
    ld_fr4(afA, &Asm[0][0][0], wm4, rd_in);
    ld_fr2(bf1, &Bsm[0][1][0], wn2, rd_in);
    ld_fr2(bf0, &Bsm[0][0][0], wn2, rd_in);

    // ---- steady state ----
    #pragma unroll 2
    for (int t = 0; t < NT - 2; ++t) {
        const int buf = t & 1, nbuf = buf ^ 1;
        // p0: MFMA(0,0); stage B0(t+1)
        STAGE_B(0, t + 1);
        BAR();
        PRIO1(); mfma_quad(acc[0][0], afA, bf0); PRIO0();
        BAR();
        // p1: issue A1 reads (drain under MFMA(0,1)); stage A0(t+2)
        ld_fr4(afB, &Asm[buf][1][0], wm4, rd_in);
        STAGE_A(0, t + 2);
        SCHEDB();
        BAR();
        PRIO1(); mfma_quad(acc[0][1], afA, bf1); PRIO0();
        BAR();
        // p2: zero reads (LDS catch-up); stage B1(t+2)
        STAGE_B(1, t + 2);
        BAR();
        PRIO1(); mfma_quad(acc[1][1], afB, bf1); PRIO0();
        BAR();
        // p3: stage A1(t+2); counted vmcnt; barrier; next-tile reads before
        //     MFMA(1,0) so they drain under it; B0 tail after (WAR on bf0).
        STAGE_A(1, t + 2);
        VMCNT6();
        BAR();
        ld_fr4(afA, &Asm[nbuf][0][0], wm4, rd_in);
        ld_fr2(bf1, &Bsm[nbuf][1][0], wn2, rd_in);
        SCHEDB();
        PRIO1(); mfma_quad(acc[1][0], afB, bf0); PRIO0();
        ld_fr2(bf0, &Bsm[nbuf][0][0], wn2, rd_in);
        BAR();
    }
    // ---- tail t = NT-2: only B0(NT-1) left to stage; full drain at p3 ----
    {
        const int t = NT - 2, buf = t & 1, nbuf = buf ^ 1;
        STAGE_B(0, t + 1);
        BAR();
        PRIO1(); mfma_quad(acc[0][0], afA, bf0); PRIO0();
        BAR();
        ld_fr4(afB, &Asm[buf][1][0], wm4, rd_in);
        SCHEDB();
        BAR();
        PRIO1(); mfma_quad(acc[0][1], afA, bf1); PRIO0();
        BAR();
        PRIO1(); mfma_quad(acc[1][1], afB, bf1); PRIO0();
        VMCNT0();
        BAR();
        ld_fr4(afA, &Asm[nbuf][0][0], wm4, rd_in);
        ld_fr2(bf1, &Bsm[nbuf][1][0], wn2, rd_in);
        SCHEDB();
        PRIO1(); mfma_quad(acc[1][0], afB, bf0); PRIO0();
        ld_fr2(bf0, &Bsm[nbuf][0][0], wn2, rd_in);
        BAR();
    }
    // ---- tail t = NT-1: pure compute ----
    {
        const int buf = (NT - 1) & 1;
        PRIO1(); mfma_quad(acc[0][0], afA, bf0); PRIO0();
        ld_fr4(afB, &Asm[buf][1][0], wm4, rd_in);
        SCHEDB();
        PRIO1(); mfma_quad(acc[0][1], afA, bf1); PRIO0();
        PRIO1(); mfma_quad(acc[1][1], afB, bf1); PRIO0();
        PRIO1(); mfma_quad(acc[1][0], afB, bf0); PRIO0();
    }
#undef STAGE_A
#undef STAGE_B

    // ---- epilogue: route cols [0,6144)->Cq, [6144,8192)->Cg (256 | 6144) ----
    unsigned short* Cc; int Nn, colbase;
    if (bx < 24) { Cc = Cq; Nn = NKV; colbase = bx * 256; }
    else         { Cc = Cg; Nn = HID; colbase = bx * 256 - NKV; }
    int row0 = by * 256 + wm * 64 + quad * 4;
    int col0 = colbase + wn * 32 + l16;
    #pragma unroll
    for (int mh = 0; mh < 2; ++mh)
        #pragma unroll
        for (int nh = 0; nh < 2; ++nh)
            #pragma unroll
            for (int mt = 0; mt < 4; ++mt)
                #pragma unroll
                for (int nt = 0; nt < 2; ++nt) {
                    int col = col0 + nh * 128 + nt * 16;
                    #pragma unroll
                    for (int r = 0; r < 4; ++r) {
                        int row = row0 + mh * 128 + mt * 16 + r;
                        Cc[(size_t)row * Nn + col] = (unsigned short)f2b(acc[mh][nh][mt][nt][r]);
                    }
                }
}

// ------- q/k RMSNorm + partial RoPE, in place. grid = B*S blocks of 256. -------
__global__ __launch_bounds__(256) void norm_rope(unsigned short* __restrict__ qkv,
                                                 const int* __restrict__ positions,
                                                 const float* __restrict__ qw,
                                                 const float* __restrict__ kw)
{
    int bs = blockIdx.x;
    int s  = bs & (S_ - 1);
    int tid = threadIdx.x;
    int l16 = tid & 15;
    unsigned short* base = qkv + (size_t)bs * NKV;
    float pos = (float)positions[s];

    #pragma unroll
    for (int p = 0; p < 2; ++p) {
        int rr = p * 16 + (tid >> 4);   // 0..31
        int qk = rr >> 4;
        int h  = rr & 15;
        unsigned short* row = base + qk * HID + h * HD;
        const float* w = qk ? kw : qw;
        uint4 v = *(const uint4*)(row + l16 * 8);
        float x[8];
        x[0] = b2f(v.x); x[1] = b2f(v.x >> 16);
        x[2] = b2f(v.y); x[3] = b2f(v.y >> 16);
        x[4] = b2f(v.z); x[5] = b2f(v.z >> 16);
        x[6] = b2f(v.w); x[7] = b2f(v.w >> 16);
        float ss = 0.f;
        #pragma unroll
        for (int t = 0; t < 8; ++t) ss += x[t] * x[t];
        ss += __shfl_xor(ss, 1); ss += __shfl_xor(ss, 2);
        ss += __shfl_xor(ss, 4); ss += __shfl_xor(ss, 8);
        float inv = rsqrtf(ss * (1.0f / 128.0f) + 1e-6f);
        float n[8];
        #pragma unroll
        for (int t = 0; t < 8; ++t) n[t] = x[t] * inv * w[l16 * 8 + t];
        float pr[8];
        #pragma unroll
        for (int t = 0; t < 8; ++t) pr[t] = __shfl_xor(n[t], 4);   // dims +-32
        if (l16 < 8) {
            #pragma unroll
            for (int t = 0; t < 8; ++t) {
                int dim = l16 * 8 + t;
                int i = dim & 31;
                float ang = pos * exp2f(-(float)i * 0.4152410118609203f);
                float cs = cosf(ang), sn = sinf(ang);
                n[t] = (dim < 32) ? (n[t] * cs - pr[t] * sn) : (n[t] * cs + pr[t] * sn);
            }
        }
        uint4 o;
        o.x = f2b(n[0]) | (f2b(n[1]) << 16);
        o.y = f2b(n[2]) | (f2b(n[3]) << 16);
        o.z = f2b(n[4]) | (f2b(n[5]) << 16);
        o.w = f2b(n[6]) | (f2b(n[7]) << 16);
        *(uint4*)(row + l16 * 8) = o;
    }
}

// ============ pass 1: per-chunk KV outer product  Wt[e][d] = sum_j kdec_j V[j][e] K[j][d]
__global__ __launch_bounds__(256) void chunk_kv(const unsigned short* __restrict__ qkv,
                                                unsigned short* __restrict__ wbuf)
{
    __shared__ unsigned short kt[128 * 72];   // kt[d][j]
    __shared__ unsigned short vt[128 * 72];   // vt[e][j] * kdec[j]
    int bi = blockIdx.x;
    int c = bi & 31, bh = bi >> 5, h = bh & 15, b = bh >> 4;
    int tid = threadIdx.x;
    float slope = -exp2f(-0.5f * (float)(h + 1)) * (1.0f + 1e-5f);

    const unsigned short* kbase = qkv + ((size_t)(b * S_ + c * CHUNK_)) * NKV + HID + h * HD;
    const unsigned short* vbase = kbase + HID;

    for (int idx = tid; idx < 4096; idx += 256) {
        int j = idx >> 6, p = idx & 63;
        unsigned int ku = *(const unsigned int*)(kbase + (size_t)j * NKV + p * 2);
        kt[(2 * p) * 72 + j]     = (unsigned short)(ku & 0xffffu);
        kt[(2 * p + 1) * 72 + j] = (unsigned short)(ku >> 16);
        float kd = expf(slope * (float)(63 - j));
        unsigned int vu = *(const unsigned int*)(vbase + (size_t)j * NKV + p * 2);
        vt[(2 * p) * 72 + j]     = (unsigned short)f2b(b2f(vu) * kd);
        vt[(2 * p + 1) * 72 + j] = (unsigned short)f2b(b2f(vu >> 16) * kd);
    }
    __syncthreads();

    int lane = tid & 63, wave = tid >> 6;
    int wm = (wave >> 1) * 64;     // e
    int wn = (wave & 1) * 64;      // d
    int l16 = lane & 15, quad = lane >> 4;

    f32x4 acc[4][4];
    #pragma unroll
    for (int i = 0; i < 4; ++i)
        #pragma unroll
        for (int j = 0; j < 4; ++j) { f32x4 z = {0.f,0.f,0.f,0.f}; acc[i][j] = z; }

    #pragma unroll
    for (int ks = 0; ks < 64; ks += 32) {
        bf16x8 af[4], bf[4];
        #pragma unroll
        for (int t = 0; t < 4; ++t) {
            af[t] = *(const bf16x8*)((const bf16_t*)vt + (wm + t * 16 + l16) * 72 + ks + quad * 8);
            bf[t] = *(const bf16x8*)((const bf16_t*)kt + (wn + t * 16 + l16) * 72 + ks + quad * 8);
        }
        #pragma unroll
        for (int mt = 0; mt < 4; ++mt)
            #pragma unroll
            for (int nt = 0; nt < 4; ++nt)
                acc[mt][nt] = __builtin_amdgcn_mfma_f32_16x16x32_bf16(af[mt], bf[nt], acc[mt][nt], 0, 0, 0);
    }

    unsigned short* wp = wbuf + ((size_t)bi << 14);  // [e][d] 128x128
    #pragma unroll
    for (int mt = 0; mt < 4; ++mt)
        #pragma unroll
        for (int nt = 0; nt < 4; ++nt) {
            int dcol = wn + nt * 16 + l16;
            #pragma unroll
            for (int r = 0; r < 4; ++r) {
                int erow = wm + mt * 16 + quad * 4 + r;
                wp[(size_t)erow * 128 + dcol] = (unsigned short)f2b(acc[mt][nt][r]);
            }
        }
}

// ============ pass 2: sequential state scan (linear recurrence), 512 blocks
__global__ __launch_bounds__(256) void state_scan(const unsigned short* __restrict__ wbuf,
                                                  const float* __restrict__ rs0,
                                                  unsigned short* __restrict__ stbuf)
{
    int bi = blockIdx.x;
    int es = bi & 15, bh = bi >> 4, h = bh & 15, b = bh >> 4;
    int tid = threadIdx.x;
    float slope = -exp2f(-0.5f * (float)(h + 1)) * (1.0f + 1e-5f);
    float lam = expf(slope * 64.0f);

    int e  = es * 8 + (tid >> 5);
    int d0 = (tid & 31) * 4;

    float S[4];
    const float* rp = rs0 + ((size_t)(b * NH + h)) * HD * HD + e;   // rstate[b][h][d][e]
    #pragma unroll
    for (int t = 0; t < 4; ++t) S[t] = rp[(size_t)(d0 + t) * HD];

    size_t off = (size_t)e * 128 + d0;
    for (int c = 0; c < NC; ++c) {
        size_t base = (((size_t)bh * NC + c) << 14) + off;
        uint2 o;
        o.x = f2b(S[0]) | (f2b(S[1]) << 16);
        o.y = f2b(S[2]) | (f2b(S[3]) << 16);
        *(uint2*)(stbuf + base) = o;
        uint2 w = *(const uint2*)(wbuf + base);
        S[0] = S[0] * lam + b2f(w.x);
        S[1] = S[1] * lam + b2f(w.x >> 16);
        S[2] = S[2] * lam + b2f(w.y);
        S[3] = S[3] * lam + b2f(w.y >> 16);
    }
}

// ============ pass 3: per-chunk output  O = (mask.QK^T)@V + qdec*(Q@S_prev)
__global__ __launch_bounds__(256) void chunk_out(const unsigned short* __restrict__ qkv,
                                                 const unsigned short* __restrict__ stbuf,
                                                 unsigned short* __restrict__ obuf)
{
    __shared__ unsigned short qs[64 * 136];   // q[i][d]
    __shared__ unsigned short vt[128 * 72];   // v^T[e][j]
    __shared__ unsigned short sc[64 * 72];    // masked scores [i][j]

    int bi = blockIdx.x;
    int c = bi & 31, bh = bi >> 5, h = bh & 15, b = bh >> 4;
    int tid = threadIdx.x;
    float slope = -exp2f(-0.5f * (float)(h + 1)) * (1.0f + 1e-5f);

    int lane = tid & 63, wave = tid >> 6;
    int l16 = lane & 15, quad = lane >> 4;
    int wn3 = wave * 32;

    // ---- prefetch st B-frags into registers FIRST: HBM latency (~900cyc) hides
    //      behind staging + scores + intra phases.
    const unsigned short* stp = stbuf + (((size_t)bh * NC + c) << 14);
    bf16x8 bsf[4][2];
    #pragma unroll
    for (int ksp4 = 0; ksp4 < 4; ++ksp4)
        #pragma unroll
        for (int nt = 0; nt < 2; ++nt)
            bsf[ksp4][nt] = *(const bf16x8*)((const bf16_t*)stp +
                (size_t)(wn3 + nt * 16 + l16) * 128 + ksp4 * 32 + quad * 8);

    const unsigned short* qrow = qkv + ((size_t)(b * S_ + c * CHUNK_)) * NKV + h * HD;
    const unsigned short* krow = qrow + HID;
    // stage q (rows of 128, padded stride 136)
    for (int idx = tid; idx < 1024; idx += 256) {
        int row = idx >> 4, c8 = (idx & 15) * 8;
        *(uint4*)(qs + row * 136 + c8) = *(const uint4*)(qrow + (size_t)row * NKV + c8);
    }
    // stage v transposed
    const unsigned short* vbase = qrow + 2 * HID;
    for (int idx = tid; idx < 4096; idx += 256) {
        int j = idx >> 6, p = idx & 63;
        unsigned int vu = *(const unsigned int*)(vbase + (size_t)j * NKV + p * 2);
        vt[(2 * p) * 72 + j]     = (unsigned short)(vu & 0xffffu);
        vt[(2 * p + 1) * 72 + j] = (unsigned short)(vu >> 16);
    }
    __syncthreads();

    // ---- scores: each wave computes rows [wave*16, +16) x all 64 j; k-frags global ----
    {
        f32x4 accS[4];
        #pragma unroll
        for (int t = 0; t < 4; ++t) { f32x4 z = {0.f,0.f,0.f,0.f}; accS[t] = z; }
        #pragma unroll
        for (int ksp = 0; ksp < 128; ksp += 32) {
            bf16x8 aq = *(const bf16x8*)((const bf16_t*)qs + (wave * 16 + l16) * 136 + ksp + quad * 8);
            #pragma unroll
            for (int nt = 0; nt < 4; ++nt) {
                bf16x8 bk = *(const bf16x8*)((const bf16_t*)krow + (size_t)(nt * 16 + l16) * NKV + ksp + quad * 8);
                accS[nt] = __builtin_amdgcn_mfma_f32_16x16x32_bf16(aq, bk, accS[nt], 0, 0, 0);
            }
        }
        float ad[4];
        #pragma unroll
        for (int r = 0; r < 4; ++r) ad[r] = expf(slope * (float)(wave * 16 + quad * 4 + r));
        #pragma unroll
        for (int nt = 0; nt < 4; ++nt) {
            int j = nt * 16 + l16;
            float bd = expf(-slope * (float)j);
            #pragma unroll
            for (int r = 0; r < 4; ++r) {
                int i = wave * 16 + quad * 4 + r;
                float v = (i >= j) ? accS[nt][r] * ad[r] * bd : 0.0f;
                sc[i * 72 + j] = (unsigned short)f2b(v);
            }
        }
    }
    __syncthreads();

    f32x4 accI[4][2], accE[4][2];
    #pragma unroll
    for (int i = 0; i < 4; ++i)
        #pragma unroll
        for (int j = 0; j < 2; ++j) { f32x4 z = {0.f,0.f,0.f,0.f}; accI[i][j] = z; accE[i][j] = z; }

    // intra: K = 64 (j)
    #pragma unroll
    for (int ksp = 0; ksp < 64; ksp += 32) {
        bf16x8 as[4], bv[2];
        #pragma unroll
        for (int mt = 0; mt < 4; ++mt)
            as[mt] = *(const bf16x8*)((const bf16_t*)sc + (mt * 16 + l16) * 72 + ksp + quad * 8);
        #pragma unroll
        for (int nt = 0; nt < 2; ++nt)
            bv[nt] = *(const bf16x8*)((const bf16_t*)vt + (wn3 + nt * 16 + l16) * 72 + ksp + quad * 8);
        #pragma unroll
        for (int mt = 0; mt < 4; ++mt)
            #pragma unroll
            for (int nt = 0; nt < 2; ++nt)
                accI[mt][nt] = __builtin_amdgcn_mfma_f32_16x16x32_bf16(as[mt], bv[nt], accI[mt][nt], 0, 0, 0);
    }
    // inter: K = 128 (d), B-frags already in registers (bsf)
    #pragma unroll
    for (int ksp4 = 0; ksp4 < 4; ++ksp4) {
        bf16x8 aq[4];
        #pragma unroll
        for (int mt = 0; mt < 4; ++mt)
            aq[mt] = *(const bf16x8*)((const bf16_t*)qs + (mt * 16 + l16) * 136 + ksp4 * 32 + quad * 8);
        #pragma unroll
        for (int mt = 0; mt < 4; ++mt)
            #pragma unroll
            for (int nt = 0; nt < 2; ++nt)
                accE[mt][nt] = __builtin_amdgcn_mfma_f32_16x16x32_bf16(aq[mt], bsf[ksp4][nt], accE[mt][nt], 0, 0, 0);
    }

    // epilogue: O = accI + qdec[i]*accE, bf16 store
    #pragma unroll
    for (int mt = 0; mt < 4; ++mt) {
        #pragma unroll
        for (int r = 0; r < 4; ++r) {
            int i = mt * 16 + quad * 4 + r;
            float qd = expf(slope * (float)(i + 1));
            int orow = b * S_ + c * CHUNK_ + i;
            #pragma unroll
            for (int nt = 0; nt < 2; ++nt) {
                int col = h * HD + wn3 + nt * 16 + l16;
                float o = accI[mt][nt][r] + qd * accE[mt][nt][r];
                obuf[(size_t)orow * 2048 + col] = (unsigned short)f2b(o);
            }
        }
    }
}

// ------- group RMSNorm + sigmoid gate: read o bf16 + gate bf16, write bf16 -------
__global__ __launch_bounds__(256) void gnorm_gate(const unsigned short* __restrict__ o,
                                                  unsigned short* __restrict__ gate,
                                                  const float* __restrict__ gw)
{
    int row = blockIdx.x >> 3;
    int g   = blockIdx.x & 7;
    int col = g * 256 + threadIdx.x;
    size_t idx = (size_t)row * 2048 + col;
    float ov = b2f(o[idx]);
    float ss = ov * ov;
    #pragma unroll
    for (int off = 32; off > 0; off >>= 1) ss += __shfl_xor(ss, off);
    __shared__ float part[4];
    if ((threadIdx.x & 63) == 0) part[threadIdx.x >> 6] = ss;
    __syncthreads();
    float tot = part[0] + part[1] + part[2] + part[3];
    float inv = rsqrtf(tot * (1.0f / 256.0f) + 1e-6f);
    float gv = b2f(gate[idx]);
    float sig = 1.0f / (1.0f + expf(-gv));
    gate[idx] = (unsigned short)f2b(ov * inv * gw[col] * sig);
}

// ---------------- launch ----------------
extern "C" void kernel_launch(void* const* d_in, const int* in_sizes, int n_in,
                              void* d_out, int out_size, void* d_ws, size_t ws_size,
                              hipStream_t stream) {
    const int*   positions = (const int*)d_in[0];
    const float* hidden    = (const float*)d_in[1];
    const float* rstate    = (const float*)d_in[2];
    const float* w_qkv     = (const float*)d_in[3];
    const float* w_g       = (const float*)d_in[4];
    const float* w_dense   = (const float*)d_in[5];
    const float* q_norm_w  = (const float*)d_in[6];
    const float* k_norm_w  = (const float*)d_in[7];
    const float* g_norm_w  = (const float*)d_in[8];
    float* out = (float*)d_out;

    const int MR = B_ * S_;  // 4096

    // ---- ws layout (total 159,383,552 B — unchanged) ----
    char* w = (char*)d_ws;
    unsigned short* qkv  = (unsigned short*)w;            w += (size_t)MR * NKV * 2;     // 50.3 MB
    unsigned short* gbuf = (unsigned short*)w;            w += (size_t)MR * 2048 * 2;    // 16.8 MB
    unsigned short* wdT  = (unsigned short*)w;            w += (size_t)HID * HID * 2;    // 8.4 MB
    char* regionA = w;                                    w += (size_t)MR * HID * 2 + (size_t)8192 * HID * 2; // 50.3 MB
    char* regionB = w;                                    // 33.6 MB
    unsigned short* hbf   = (unsigned short*)regionA;                                 // 16.8 MB
    unsigned short* btQG  = (unsigned short*)(regionA + (size_t)MR * HID * 2);        // [8192][2048] 33.5 MB
    unsigned short* wqT   = btQG;                                                     // rows 0..6143
    unsigned short* wgT   = btQG + (size_t)NKV * HID;                                 // rows 6144..8191
    unsigned short* stbuf = (unsigned short*)regionA;     // 32 MB, after GEMMs
    unsigned short* wbuf  = (unsigned short*)regionB;     // 32 MB
    unsigned short* obuf  = (unsigned short*)regionB;     // 16.8 MB, after pass2

    // ---- conversions ----
    cvt_bf16<<<dim3((MR * HID / 8 + 255) / 256), dim3(256), 0, stream>>>(hidden, hbf, MR * HID / 8);
    transpose_cvt<<<dim3((HID / 32) * (NKV / 32)), dim3(256), 0, stream>>>(w_qkv, wqT, HID, NKV);
    transpose_cvt<<<dim3((HID / 32) * (HID / 32)), dim3(256), 0, stream>>>(w_g, wgT, HID, HID);
    transpose_cvt<<<dim3((HID / 32) * (HID / 32)), dim3(256), 0, stream>>>(w_dense, wdT, HID, HID);

    // ---- fused qkv+gate projection: 256^2 8-phase (512 wg x 512 thr) ----
    gemm_qg_256<<<dim3(512), dim3(512), 0, stream>>>(
        (const bf16_t*)hbf, (const bf16_t*)btQG, qkv, gbuf);
    // ---- q/k norm + rope (in place) ----
    norm_rope<<<dim3(B_ * S_), dim3(256), 0, stream>>>(qkv, positions, q_norm_w, k_norm_w);

    // ---- attention: 3-pass chunked scan ----
    chunk_kv<<<dim3(B_ * NH * NC), dim3(256), 0, stream>>>(qkv, wbuf);
    state_scan<<<dim3(B_ * NH * 16), dim3(256), 0, stream>>>(wbuf, rstate, stbuf);
    chunk_out<<<dim3(B_ * NH * NC), dim3(256), 0, stream>>>(qkv, stbuf, obuf);

    // ---- group norm + gate ----
    gnorm_gate<<<dim3(MR * GROUPS_), dim3(256), 0, stream>>>(obuf, gbuf, g_norm_w);
    // ---- output projection (fp32 out) ----
    gemm_mfma<float><<<dim3((MR / 128) * (HID / 128)), dim3(256), 0, stream>>>(
        (const bf16_t*)gbuf, (const bf16_t*)wdT, out, MR, HID, HID);
}

// Round 3
// 459.017 us; speedup vs baseline: 1.0717x; 1.0125x over previous
//
#include <hip/hip_runtime.h>
#include <hip/hip_bf16.h>
#include <math.h>

// ---- problem constants ----
#define NH   16
#define HD   128
#define HID  2048
#define NKV  6144      // 3*NH*HD
#define B_   2
#define S_   2048
#define NC   32        // S/CHUNK
#define CHUNK_ 64
#define GROUPS_ 8

typedef __bf16 bf16_t;
typedef bf16_t bf16x8 __attribute__((ext_vector_type(8)));
typedef float  f32x4  __attribute__((ext_vector_type(4)));

__device__ __forceinline__ float b2f(unsigned int u) {
    union { unsigned int u; float f; } c; c.u = (u & 0xffffu) << 16; return c.f;
}
__device__ __forceinline__ unsigned int f2b(float f) {
    union { float f; unsigned int u; } c; c.f = f;
    unsigned int u = c.u;
    return (u + 0x7fffu + ((u >> 16) & 1u)) >> 16;
}

#define GLOAD_LDS16(gp, lp) __builtin_amdgcn_global_load_lds(                     \
    (const __attribute__((address_space(1))) void*)(gp),                          \
    (__attribute__((address_space(3))) void*)(lp), 16, 0, 0)

// ---------------- fp32 -> bf16 elementwise (8 elems/thread) ----------------
__global__ __launch_bounds__(256) void cvt_bf16(const float* __restrict__ in,
                                                unsigned short* __restrict__ out, int n8)
{
    int i = blockIdx.x * 256 + threadIdx.x;
    if (i >= n8) return;
    const float4* p = (const float4*)in + (size_t)i * 2;
    float4 a = p[0], b = p[1];
    uint4 o;
    o.x = f2b(a.x) | (f2b(a.y) << 16);
    o.y = f2b(a.z) | (f2b(a.w) << 16);
    o.z = f2b(b.x) | (f2b(b.y) << 16);
    o.w = f2b(b.z) | (f2b(b.w) << 16);
    ((uint4*)out)[i] = o;
}

// ------------- fp32 [K][N] -> bf16 [N][K] transpose (32x32 tiles) ---------------
__global__ __launch_bounds__(256) void transpose_cvt(const float* __restrict__ in,
                                                     unsigned short* __restrict__ out,
                                                     int Kdim, int Ndim)
{
    __shared__ float tile[32][33];
    int ntx = Ndim >> 5;
    int bx = blockIdx.x % ntx;
    int by = blockIdx.x / ntx;
    int lx = threadIdx.x & 31, ly = threadIdx.x >> 5;
    int r0 = by * 32, c0 = bx * 32;
    #pragma unroll
    for (int r = 0; r < 4; ++r)
        tile[ly + r * 8][lx] = in[(size_t)(r0 + ly + r * 8) * Ndim + c0 + lx];
    __syncthreads();
    #pragma unroll
    for (int r = 0; r < 4; ++r)
        out[(size_t)(c0 + ly + r * 8) * Kdim + r0 + lx] = (unsigned short)f2b(tile[lx][ly + r * 8]);
}

// ---------------- MFMA GEMM (plain): C[M,N] = A[M,K] @ Bt[N,K]^T ----------------
__device__ __forceinline__ void storeOne(float* p, float v) { *p = v; }
__device__ __forceinline__ void storeOne(unsigned short* p, float v) { *p = (unsigned short)f2b(v); }

template <typename OutT>
__global__ __launch_bounds__(256) void gemm_mfma(const bf16_t* __restrict__ A,   // [M][K]
                                                 const bf16_t* __restrict__ Bt,  // [N][K]
                                                 OutT* __restrict__ C,           // [M][N]
                                                 int M, int N, int K)
{
    __shared__ bf16_t As[128 * 32];
    __shared__ bf16_t Bs[128 * 32];
    int tid  = threadIdx.x;
    int ntiles = N >> 7;
    int bx = blockIdx.x % ntiles;
    int by = blockIdx.x / ntiles;
    int lane = tid & 63;
    int wave = tid >> 6;
    int wm = (wave >> 1) * 64;
    int wn = (wave & 1) * 64;
    int l16  = lane & 15;
    int quad = lane >> 4;

    f32x4 acc[4][4];
    #pragma unroll
    for (int i = 0; i < 4; ++i)
        #pragma unroll
        for (int j = 0; j < 4; ++j) { f32x4 z = {0.f, 0.f, 0.f, 0.f}; acc[i][j] = z; }

    const bf16_t* aG = A  + (size_t)(by * 128 + (tid >> 2)) * K + (tid & 3) * 8;
    const bf16_t* bG = Bt + (size_t)(bx * 128 + (tid >> 2)) * K + (tid & 3) * 8;
    bf16_t* aL0 = As + tid * 8;
    bf16_t* aL1 = As + 2048 + tid * 8;
    bf16_t* bL0 = Bs + tid * 8;
    bf16_t* bL1 = Bs + 2048 + tid * 8;
    const size_t half = (size_t)64 * K;

    for (int kt = 0; kt < K; kt += 32) {
        GLOAD_LDS16(aG + kt,        aL0);
        GLOAD_LDS16(aG + half + kt, aL1);
        GLOAD_LDS16(bG + kt,        bL0);
        GLOAD_LDS16(bG + half + kt, bL1);
        __syncthreads();
        bf16x8 af[4], bf[4];
        #pragma unroll
        for (int t = 0; t < 4; ++t) {
            af[t] = *(const bf16x8*)(As + (wm + t * 16 + l16) * 32 + quad * 8);
            bf[t] = *(const bf16x8*)(Bs + (wn + t * 16 + l16) * 32 + quad * 8);
        }
        #pragma unroll
        for (int mt = 0; mt < 4; ++mt)
            #pragma unroll
            for (int nt = 0; nt < 4; ++nt)
                acc[mt][nt] = __builtin_amdgcn_mfma_f32_16x16x32_bf16(af[mt], bf[nt], acc[mt][nt], 0, 0, 0);
        __syncthreads();
    }

    #pragma unroll
    for (int mt = 0; mt < 4; ++mt)
        #pragma unroll
        for (int nt = 0; nt < 4; ++nt) {
            int col = bx * 128 + wn + nt * 16 + l16;
            #pragma unroll
            for (int r = 0; r < 4; ++r) {
                int row = by * 128 + wm + mt * 16 + quad * 4 + r;
                storeOne(C + (size_t)row * N + col, acc[mt][nt][r]);
            }
        }
}

// ================= 256x256 barrier-light GEMM (qkv+gate fused) ===============
// v3: depth-1 prefetch -> ONE barrier per K-tile, zero intra-tile barriers.
// Round-2 postmortem: phase barriers forced lockstep; LDS service (2304cyc/
// CU/Ktile) and MFMA (2048cyc) ran serially + 8 barriers/tile of sync cost =
// 5660 cyc/tile. Now: tile t stages t+1 into nbuf (writes) while all frag
// reads hit buf (disjoint -> no WAR within tile); one vmcnt(0)+s_barrier per
// tile (stage loads issued a full tile (~2300cyc) before the wait -> HBM
// latency fully hidden). The whole tile is one scheduling region: compiler
// emits counted lgkmcnt between ds_read and MFMA (m97 asm evidence), so LDS
// drains under MFMA within and across waves.
// Cross-tile WAR safety: each wave's buf-reads are consumed by MFMAs (lgkm-
// waited) before it reaches the barrier; after the barrier all waves' reads
// are complete, so next tile's stages into buf are safe.

__device__ __forceinline__ void ld_fr4(bf16x8 (&d)[4][2], const bf16_t* b, int s0, int ri) {
    #pragma unroll
    for (int i = 0; i < 4; ++i)
        #pragma unroll
        for (int k = 0; k < 2; ++k)
            d[i][k] = *(const bf16x8*)(b + (((s0 + i) * 2 + k) << 9) + ri);
}
__device__ __forceinline__ void ld_fr2(bf16x8 (&d)[2][2], const bf16_t* b, int s0, int ri) {
    #pragma unroll
    for (int i = 0; i < 2; ++i)
        #pragma unroll
        for (int k = 0; k < 2; ++k)
            d[i][k] = *(const bf16x8*)(b + (((s0 + i) * 2 + k) << 9) + ri);
}
__device__ __forceinline__ void mfma_quad(f32x4 (&a)[4][2], const bf16x8 (&af)[4][2],
                                          const bf16x8 (&bv)[2][2]) {
    #pragma unroll
    for (int mt = 0; mt < 4; ++mt)
        #pragma unroll
        for (int nt = 0; nt < 2; ++nt)
            #pragma unroll
            for (int ks = 0; ks < 2; ++ks)
                a[mt][nt] = __builtin_amdgcn_mfma_f32_16x16x32_bf16(af[mt][ks], bv[nt][ks], a[mt][nt], 0, 0, 0);
}

#define BAR()     asm volatile("s_barrier" ::: "memory")
#define VMCNT0()  asm volatile("s_waitcnt vmcnt(0)" ::: "memory")

__global__ __launch_bounds__(512, 2) void gemm_qg_256(const bf16_t* __restrict__ A,
                                                      const bf16_t* __restrict__ Bt,
                                                      unsigned short* __restrict__ Cq,
                                                      unsigned short* __restrict__ Cg)
{
    __shared__ bf16_t Asm[2][2][8192];   // [buf][half][128*64]
    __shared__ bf16_t Bsm[2][2][8192];
    const int K  = HID;       // 2048
    const int NT = K / 64;    // 32 K-tiles

    int tid  = threadIdx.x;
    int wave = tid >> 6, lane = tid & 63;
    int wm = wave >> 2, wn = wave & 3;            // 2 M-waves x 4 N-waves
    int l16 = lane & 15, quad = lane >> 4;
    int wm4 = wm * 4, wn2 = wn * 2;

    // XCD-aware mapping: each XCD (bid&7) owns an 8x8 (by,bx) tile block ->
    // ~8.4MB A + 8.4MB B per XCD. 512 = 8*64 exact -> bijective.
    int bid = blockIdx.x;
    int xcd = bid & 7, idx = bid >> 3;            // idx in 0..63
    int by  = (xcd >> 2) * 8 + (idx >> 3);        // 0..15
    int bx  = (xcd & 3) * 8 + (idx & 7);          // 0..31

    // swizzled within-subtile read offset (elems): row l16, col quad*8
    int rd_in = ((l16 << 5) | (quad << 3)) ^ (((l16 >> 3) & 1) << 4);

    // pre-swizzled global source decode for global_load_lds (one subtile/instr)
    int ch = lane ^ ((lane & 32) >> 4);
    int rr = ch >> 2;            // row within 16-row subtile
    int cc = (ch & 3) * 8;       // col (elems) within 32-col subtile

    // wave stages subtile row-block R=wave (C=0,1) of each half-tile
    const bf16_t* aSrc0 = A  + (size_t)(by * 256 +       wave * 16 + rr) * K + cc;
    const bf16_t* aSrc1 = A  + (size_t)(by * 256 + 128 + wave * 16 + rr) * K + cc;
    const bf16_t* bSrc0 = Bt + (size_t)(bx * 256 +       wave * 16 + rr) * K + cc;
    const bf16_t* bSrc1 = Bt + (size_t)(bx * 256 + 128 + wave * 16 + rr) * K + cc;

#define STAGE_A(h, t) do {                                                        \
        const bf16_t* _g = ((h) ? aSrc1 : aSrc0) + (size_t)(t) * 64;              \
        bf16_t* _l = &Asm[(t) & 1][(h)][wave * 1024 + lane * 8];                  \
        GLOAD_LDS16(_g,      _l);                                                 \
        GLOAD_LDS16(_g + 32, _l + 512); } while (0)
#define STAGE_B(h, t) do {                                                        \
        const bf16_t* _g = ((h) ? bSrc1 : bSrc0) + (size_t)(t) * 64;              \
        bf16_t* _l = &Bsm[(t) & 1][(h)][wave * 1024 + lane * 8];                  \
        GLOAD_LDS16(_g,      _l);                                                 \
        GLOAD_LDS16(_g + 32, _l + 512); } while (0)

    f32x4 acc[2][2][4][2];
    #pragma unroll
    for (int a0 = 0; a0 < 2; ++a0)
        #pragma unroll
        for (int a1 = 0; a1 < 2; ++a1)
            #pragma unroll
            for (int a2 = 0; a2 < 4; ++a2)
                #pragma unroll
                for (int a3 = 0; a3 < 2; ++a3) { f32x4 z = {0.f,0.f,0.f,0.f}; acc[a0][a1][a2][a3] = z; }

    // ---- prologue: stage tile 0, drain, sync ----
    STAGE_A(0, 0); STAGE_B(0, 0); STAGE_A(1, 0); STAGE_B(1, 0);
    VMCNT0();
    BAR();

    // ---- main loop: one barrier per K-tile; reads buf, stages nbuf ----
    #pragma unroll 2
    for (int t = 0; t < NT - 1; ++t) {
        const int buf = t & 1;
        // prefetch next tile (writes nbuf only; disjoint from this tile's reads)
        STAGE_A(0, t + 1); STAGE_B(0, t + 1); STAGE_A(1, t + 1); STAGE_B(1, t + 1);
        // compute tile t: compiler free to interleave ds_read and MFMA with
        // counted lgkmcnt; no intra-tile barriers.
        {
            bf16x8 afA[4][2], afB[4][2], bf0[2][2], bf1[2][2];
            ld_fr4(afA, &Asm[buf][0][0], wm4, rd_in);
            ld_fr2(bf0, &Bsm[buf][0][0], wn2, rd_in);
            mfma_quad(acc[0][0], afA, bf0);
            ld_fr2(bf1, &Bsm[buf][1][0], wn2, rd_in);
            mfma_quad(acc[0][1], afA, bf1);
            ld_fr4(afB, &Asm[buf][1][0], wm4, rd_in);
            mfma_quad(acc[1][1], afB, bf1);
            mfma_quad(acc[1][0], afB, bf0);
        }
        VMCNT0();   // stage loads issued a full tile ago -> latency already hidden
        BAR();
    }
    // ---- tail tile NT-1: pure compute ----
    {
        const int buf = (NT - 1) & 1;
        bf16x8 afA[4][2], afB[4][2], bf0[2][2], bf1[2][2];
        ld_fr4(afA, &Asm[buf][0][0], wm4, rd_in);
        ld_fr2(bf0, &Bsm[buf][0][0], wn2, rd_in);
        mfma_quad(acc[0][0], afA, bf0);
        ld_fr2(bf1, &Bsm[buf][1][0], wn2, rd_in);
        mfma_quad(acc[0][1], afA, bf1);
        ld_fr4(afB, &Asm[buf][1][0], wm4, rd_in);
        mfma_quad(acc[1][1], afB, bf1);
        mfma_quad(acc[1][0], afB, bf0);
    }
#undef STAGE_A
#undef STAGE_B

    // ---- epilogue: route cols [0,6144)->Cq, [6144,8192)->Cg (256 | 6144) ----
    unsigned short* Cc; int Nn, colbase;
    if (bx < 24) { Cc = Cq; Nn = NKV; colbase = bx * 256; }
    else         { Cc = Cg; Nn = HID; colbase = bx * 256 - NKV; }
    int row0 = by * 256 + wm * 64 + quad * 4;
    int col0 = colbase + wn * 32 + l16;
    #pragma unroll
    for (int mh = 0; mh < 2; ++mh)
        #pragma unroll
        for (int nh = 0; nh < 2; ++nh)
            #pragma unroll
            for (int mt = 0; mt < 4; ++mt)
                #pragma unroll
                for (int nt = 0; nt < 2; ++nt) {
                    int col = col0 + nh * 128 + nt * 16;
                    #pragma unroll
                    for (int r = 0; r < 4; ++r) {
                        int row = row0 + mh * 128 + mt * 16 + r;
                        Cc[(size_t)row * Nn + col] = (unsigned short)f2b(acc[mh][nh][mt][nt][r]);
                    }
                }
}

// ------- q/k RMSNorm + partial RoPE, in place. grid = B*S blocks of 256. -------
__global__ __launch_bounds__(256) void norm_rope(unsigned short* __restrict__ qkv,
                                                 const int* __restrict__ positions,
                                                 const float* __restrict__ qw,
                                                 const float* __restrict__ kw)
{
    int bs = blockIdx.x;
    int s  = bs & (S_ - 1);
    int tid = threadIdx.x;
    int l16 = tid & 15;
    unsigned short* base = qkv + (size_t)bs * NKV;
    float pos = (float)positions[s];

    #pragma unroll
    for (int p = 0; p < 2; ++p) {
        int rr = p * 16 + (tid >> 4);   // 0..31
        int qk = rr >> 4;
        int h  = rr & 15;
        unsigned short* row = base + qk * HID + h * HD;
        const float* w = qk ? kw : qw;
        uint4 v = *(const uint4*)(row + l16 * 8);
        float x[8];
        x[0] = b2f(v.x); x[1] = b2f(v.x >> 16);
        x[2] = b2f(v.y); x[3] = b2f(v.y >> 16);
        x[4] = b2f(v.z); x[5] = b2f(v.z >> 16);
        x[6] = b2f(v.w); x[7] = b2f(v.w >> 16);
        float ss = 0.f;
        #pragma unroll
        for (int t = 0; t < 8; ++t) ss += x[t] * x[t];
        ss += __shfl_xor(ss, 1); ss += __shfl_xor(ss, 2);
        ss += __shfl_xor(ss, 4); ss += __shfl_xor(ss, 8);
        float inv = rsqrtf(ss * (1.0f / 128.0f) + 1e-6f);
        float n[8];
        #pragma unroll
        for (int t = 0; t < 8; ++t) n[t] = x[t] * inv * w[l16 * 8 + t];
        float pr[8];
        #pragma unroll
        for (int t = 0; t < 8; ++t) pr[t] = __shfl_xor(n[t], 4);   // dims +-32
        if (l16 < 8) {
            #pragma unroll
            for (int t = 0; t < 8; ++t) {
                int dim = l16 * 8 + t;
                int i = dim & 31;
                float ang = pos * exp2f(-(float)i * 0.4152410118609203f);
                float cs = cosf(ang), sn = sinf(ang);
                n[t] = (dim < 32) ? (n[t] * cs - pr[t] * sn) : (n[t] * cs + pr[t] * sn);
            }
        }
        uint4 o;
        o.x = f2b(n[0]) | (f2b(n[1]) << 16);
        o.y = f2b(n[2]) | (f2b(n[3]) << 16);
        o.z = f2b(n[4]) | (f2b(n[5]) << 16);
        o.w = f2b(n[6]) | (f2b(n[7]) << 16);
        *(uint4*)(row + l16 * 8) = o;
    }
}

// ============ pass 1: per-chunk KV outer product  Wt[e][d] = sum_j kdec_j V[j][e] K[j][d]
__global__ __launch_bounds__(256) void chunk_kv(const unsigned short* __restrict__ qkv,
                                                unsigned short* __restrict__ wbuf)
{
    __shared__ unsigned short kt[128 * 72];   // kt[d][j]
    __shared__ unsigned short vt[128 * 72];   // vt[e][j] * kdec[j]
    int bi = blockIdx.x;
    int c = bi & 31, bh = bi >> 5, h = bh & 15, b = bh >> 4;
    int tid = threadIdx.x;
    float slope = -exp2f(-0.5f * (float)(h + 1)) * (1.0f + 1e-5f);

    const unsigned short* kbase = qkv + ((size_t)(b * S_ + c * CHUNK_)) * NKV + HID + h * HD;
    const unsigned short* vbase = kbase + HID;

    for (int idx = tid; idx < 4096; idx += 256) {
        int j = idx >> 6, p = idx & 63;
        unsigned int ku = *(const unsigned int*)(kbase + (size_t)j * NKV + p * 2);
        kt[(2 * p) * 72 + j]     = (unsigned short)(ku & 0xffffu);
        kt[(2 * p + 1) * 72 + j] = (unsigned short)(ku >> 16);
        float kd = expf(slope * (float)(63 - j));
        unsigned int vu = *(const unsigned int*)(vbase + (size_t)j * NKV + p * 2);
        vt[(2 * p) * 72 + j]     = (unsigned short)f2b(b2f(vu) * kd);
        vt[(2 * p + 1) * 72 + j] = (unsigned short)f2b(b2f(vu >> 16) * kd);
    }
    __syncthreads();

    int lane = tid & 63, wave = tid >> 6;
    int wm = (wave >> 1) * 64;     // e
    int wn = (wave & 1) * 64;      // d
    int l16 = lane & 15, quad = lane >> 4;

    f32x4 acc[4][4];
    #pragma unroll
    for (int i = 0; i < 4; ++i)
        #pragma unroll
        for (int j = 0; j < 4; ++j) { f32x4 z = {0.f,0.f,0.f,0.f}; acc[i][j] = z; }

    #pragma unroll
    for (int ks = 0; ks < 64; ks += 32) {
        bf16x8 af[4], bf[4];
        #pragma unroll
        for (int t = 0; t < 4; ++t) {
            af[t] = *(const bf16x8*)((const bf16_t*)vt + (wm + t * 16 + l16) * 72 + ks + quad * 8);
            bf[t] = *(const bf16x8*)((const bf16_t*)kt + (wn + t * 16 + l16) * 72 + ks + quad * 8);
        }
        #pragma unroll
        for (int mt = 0; mt < 4; ++mt)
            #pragma unroll
            for (int nt = 0; nt < 4; ++nt)
                acc[mt][nt] = __builtin_amdgcn_mfma_f32_16x16x32_bf16(af[mt], bf[nt], acc[mt][nt], 0, 0, 0);
    }

    unsigned short* wp = wbuf + ((size_t)bi << 14);  // [e][d] 128x128
    #pragma unroll
    for (int mt = 0; mt < 4; ++mt)
        #pragma unroll
        for (int nt = 0; nt < 4; ++nt) {
            int dcol = wn + nt * 16 + l16;
            #pragma unroll
            for (int r = 0; r < 4; ++r) {
                int erow = wm + mt * 16 + quad * 4 + r;
                wp[(size_t)erow * 128 + dcol] = (unsigned short)f2b(acc[mt][nt][r]);
            }
        }
}

// ============ pass 2: sequential state scan (linear recurrence), 512 blocks
__global__ __launch_bounds__(256) void state_scan(const unsigned short* __restrict__ wbuf,
                                                  const float* __restrict__ rs0,
                                                  unsigned short* __restrict__ stbuf)
{
    int bi = blockIdx.x;
    int es = bi & 15, bh = bi >> 4, h = bh & 15, b = bh >> 4;
    int tid = threadIdx.x;
    float slope = -exp2f(-0.5f * (float)(h + 1)) * (1.0f + 1e-5f);
    float lam = expf(slope * 64.0f);

    int e  = es * 8 + (tid >> 5);
    int d0 = (tid & 31) * 4;

    float S[4];
    const float* rp = rs0 + ((size_t)(b * NH + h)) * HD * HD + e;   // rstate[b][h][d][e]
    #pragma unroll
    for (int t = 0; t < 4; ++t) S[t] = rp[(size_t)(d0 + t) * HD];

    size_t off = (size_t)e * 128 + d0;
    for (int c = 0; c < NC; ++c) {
        size_t base = (((size_t)bh * NC + c) << 14) + off;
        uint2 o;
        o.x = f2b(S[0]) | (f2b(S[1]) << 16);
        o.y = f2b(S[2]) | (f2b(S[3]) << 16);
        *(uint2*)(stbuf + base) = o;
        uint2 w = *(const uint2*)(wbuf + base);
        S[0] = S[0] * lam + b2f(w.x);
        S[1] = S[1] * lam + b2f(w.x >> 16);
        S[2] = S[2] * lam + b2f(w.y);
        S[3] = S[3] * lam + b2f(w.y >> 16);
    }
}

// ============ pass 3: per-chunk output  O = (mask.QK^T)@V + qdec*(Q@S_prev)
__global__ __launch_bounds__(256) void chunk_out(const unsigned short* __restrict__ qkv,
                                                 const unsigned short* __restrict__ stbuf,
                                                 unsigned short* __restrict__ obuf)
{
    __shared__ unsigned short qs[64 * 136];   // q[i][d]
    __shared__ unsigned short vt[128 * 72];   // v^T[e][j]
    __shared__ unsigned short sc[64 * 72];    // masked scores [i][j]

    int bi = blockIdx.x;
    int c = bi & 31, bh = bi >> 5, h = bh & 15, b = bh >> 4;
    int tid = threadIdx.x;
    float slope = -exp2f(-0.5f * (float)(h + 1)) * (1.0f + 1e-5f);

    int lane = tid & 63, wave = tid >> 6;
    int l16 = lane & 15, quad = lane >> 4;
    int wn3 = wave * 32;

    // ---- prefetch st B-frags into registers FIRST: HBM latency (~900cyc) hides
    //      behind staging + scores + intra phases.
    const unsigned short* stp = stbuf + (((size_t)bh * NC + c) << 14);
    bf16x8 bsf[4][2];
    #pragma unroll
    for (int ksp4 = 0; ksp4 < 4; ++ksp4)
        #pragma unroll
        for (int nt = 0; nt < 2; ++nt)
            bsf[ksp4][nt] = *(const bf16x8*)((const bf16_t*)stp +
                (size_t)(wn3 + nt * 16 + l16) * 128 + ksp4 * 32 + quad * 8);

    const unsigned short* qrow = qkv + ((size_t)(b * S_ + c * CHUNK_)) * NKV + h * HD;
    const unsigned short* krow = qrow + HID;
    // stage q (rows of 128, padded stride 136)
    for (int idx = tid; idx < 1024; idx += 256) {
        int row = idx >> 4, c8 = (idx & 15) * 8;
        *(uint4*)(qs + row * 136 + c8) = *(const uint4*)(qrow + (size_t)row * NKV + c8);
    }
    // stage v transposed
    const unsigned short* vbase = qrow + 2 * HID;
    for (int idx = tid; idx < 4096; idx += 256) {
        int j = idx >> 6, p = idx & 63;
        unsigned int vu = *(const unsigned int*)(vbase + (size_t)j * NKV + p * 2);
        vt[(2 * p) * 72 + j]     = (unsigned short)(vu & 0xffffu);
        vt[(2 * p + 1) * 72 + j] = (unsigned short)(vu >> 16);
    }
    __syncthreads();

    // ---- scores: each wave computes rows [wave*16, +16) x all 64 j; k-frags global ----
    {
        f32x4 accS[4];
        #pragma unroll
        for (int t = 0; t < 4; ++t) { f32x4 z = {0.f,0.f,0.f,0.f}; accS[t] = z; }
        #pragma unroll
        for (int ksp = 0; ksp < 128; ksp += 32) {
            bf16x8 aq = *(const bf16x8*)((const bf16_t*)qs + (wave * 16 + l16) * 136 + ksp + quad * 8);
            #pragma unroll
            for (int nt = 0; nt < 4; ++nt) {
                bf16x8 bk = *(const bf16x8*)((const bf16_t*)krow + (size_t)(nt * 16 + l16) * NKV + ksp + quad * 8);
                accS[nt] = __builtin_amdgcn_mfma_f32_16x16x32_bf16(aq, bk, accS[nt], 0, 0, 0);
            }
        }
        float ad[4];
        #pragma unroll
        for (int r = 0; r < 4; ++r) ad[r] = expf(slope * (float)(wave * 16 + quad * 4 + r));
        #pragma unroll
        for (int nt = 0; nt < 4; ++nt) {
            int j = nt * 16 + l16;
            float bd = expf(-slope * (float)j);
            #pragma unroll
            for (int r = 0; r < 4; ++r) {
                int i = wave * 16 + quad * 4 + r;
                float v = (i >= j) ? accS[nt][r] * ad[r] * bd : 0.0f;
                sc[i * 72 + j] = (unsigned short)f2b(v);
            }
        }
    }
    __syncthreads();

    f32x4 accI[4][2], accE[4][2];
    #pragma unroll
    for (int i = 0; i < 4; ++i)
        #pragma unroll
        for (int j = 0; j < 2; ++j) { f32x4 z = {0.f,0.f,0.f,0.f}; accI[i][j] = z; accE[i][j] = z; }

    // intra: K = 64 (j)
    #pragma unroll
    for (int ksp = 0; ksp < 64; ksp += 32) {
        bf16x8 as[4], bv[2];
        #pragma unroll
        for (int mt = 0; mt < 4; ++mt)
            as[mt] = *(const bf16x8*)((const bf16_t*)sc + (mt * 16 + l16) * 72 + ksp + quad * 8);
        #pragma unroll
        for (int nt = 0; nt < 2; ++nt)
            bv[nt] = *(const bf16x8*)((const bf16_t*)vt + (wn3 + nt * 16 + l16) * 72 + ksp + quad * 8);
        #pragma unroll
        for (int mt = 0; mt < 4; ++mt)
            #pragma unroll
            for (int nt = 0; nt < 2; ++nt)
                accI[mt][nt] = __builtin_amdgcn_mfma_f32_16x16x32_bf16(as[mt], bv[nt], accI[mt][nt], 0, 0, 0);
    }
    // inter: K = 128 (d), B-frags already in registers (bsf)
    #pragma unroll
    for (int ksp4 = 0; ksp4 < 4; ++ksp4) {
        bf16x8 aq[4];
        #pragma unroll
        for (int mt = 0; mt < 4; ++mt)
            aq[mt] = *(const bf16x8*)((const bf16_t*)qs + (mt * 16 + l16) * 136 + ksp4 * 32 + quad * 8);
        #pragma unroll
        for (int mt = 0; mt < 4; ++mt)
            #pragma unroll
            for (int nt = 0; nt < 2; ++nt)
                accE[mt][nt] = __builtin_amdgcn_mfma_f32_16x16x32_bf16(aq[mt], bsf[ksp4][nt], accE[mt][nt], 0, 0, 0);
    }

    // epilogue: O = accI + qdec[i]*accE, bf16 store
    #pragma unroll
    for (int mt = 0; mt < 4; ++mt) {
        #pragma unroll
        for (int r = 0; r < 4; ++r) {
            int i = mt * 16 + quad * 4 + r;
            float qd = expf(slope * (float)(i + 1));
            int orow = b * S_ + c * CHUNK_ + i;
            #pragma unroll
            for (int nt = 0; nt < 2; ++nt) {
                int col = h * HD + wn3 + nt * 16 + l16;
                float o = accI[mt][nt][r] + qd * accE[mt][nt][r];
                obuf[(size_t)orow * 2048 + col] = (unsigned short)f2b(o);
            }
        }
    }
}

// ------- group RMSNorm + sigmoid gate: read o bf16 + gate bf16, write bf16 -------
__global__ __launch_bounds__(256) void gnorm_gate(const unsigned short* __restrict__ o,
                                                  unsigned short* __restrict__ gate,
                                                  const float* __restrict__ gw)
{
    int row = blockIdx.x >> 3;
    int g   = blockIdx.x & 7;
    int col = g * 256 + threadIdx.x;
    size_t idx = (size_t)row * 2048 + col;
    float ov = b2f(o[idx]);
    float ss = ov * ov;
    #pragma unroll
    for (int off = 32; off > 0; off >>= 1) ss += __shfl_xor(ss, off);
    __shared__ float part[4];
    if ((threadIdx.x & 63) == 0) part[threadIdx.x >> 6] = ss;
    __syncthreads();
    float tot = part[0] + part[1] + part[2] + part[3];
    float inv = rsqrtf(tot * (1.0f / 256.0f) + 1e-6f);
    float gv = b2f(gate[idx]);
    float sig = 1.0f / (1.0f + expf(-gv));
    gate[idx] = (unsigned short)f2b(ov * inv * gw[col] * sig);
}

// ---------------- launch ----------------
extern "C" void kernel_launch(void* const* d_in, const int* in_sizes, int n_in,
                              void* d_out, int out_size, void* d_ws, size_t ws_size,
                              hipStream_t stream) {
    const int*   positions = (const int*)d_in[0];
    const float* hidden    = (const float*)d_in[1];
    const float* rstate    = (const float*)d_in[2];
    const float* w_qkv     = (const float*)d_in[3];
    const float* w_g       = (const float*)d_in[4];
    const float* w_dense   = (const float*)d_in[5];
    const float* q_norm_w  = (const float*)d_in[6];
    const float* k_norm_w  = (const float*)d_in[7];
    const float* g_norm_w  = (const float*)d_in[8];
    float* out = (float*)d_out;

    const int MR = B_ * S_;  // 4096

    // ---- ws layout (total 159,383,552 B — unchanged) ----
    char* w = (char*)d_ws;
    unsigned short* qkv  = (unsigned short*)w;            w += (size_t)MR * NKV * 2;     // 50.3 MB
    unsigned short* gbuf = (unsigned short*)w;            w += (size_t)MR * 2048 * 2;    // 16.8 MB
    unsigned short* wdT  = (unsigned short*)w;            w += (size_t)HID * HID * 2;    // 8.4 MB
    char* regionA = w;                                    w += (size_t)MR * HID * 2 + (size_t)8192 * HID * 2; // 50.3 MB
    char* regionB = w;                                    // 33.6 MB
    unsigned short* hbf   = (unsigned short*)regionA;                                 // 16.8 MB
    unsigned short* btQG  = (unsigned short*)(regionA + (size_t)MR * HID * 2);        // [8192][2048] 33.5 MB
    unsigned short* wqT   = btQG;                                                     // rows 0..6143
    unsigned short* wgT   = btQG + (size_t)NKV * HID;                                 // rows 6144..8191
    unsigned short* stbuf = (unsigned short*)regionA;     // 32 MB, after GEMMs
    unsigned short* wbuf  = (unsigned short*)regionB;     // 32 MB
    unsigned short* obuf  = (unsigned short*)regionB;     // 16.8 MB, after pass2

    // ---- conversions ----
    cvt_bf16<<<dim3((MR * HID / 8 + 255) / 256), dim3(256), 0, stream>>>(hidden, hbf, MR * HID / 8);
    transpose_cvt<<<dim3((HID / 32) * (NKV / 32)), dim3(256), 0, stream>>>(w_qkv, wqT, HID, NKV);
    transpose_cvt<<<dim3((HID / 32) * (HID / 32)), dim3(256), 0, stream>>>(w_g, wgT, HID, HID);
    transpose_cvt<<<dim3((HID / 32) * (HID / 32)), dim3(256), 0, stream>>>(w_dense, wdT, HID, HID);

    // ---- fused qkv+gate projection: 256^2 barrier-light (512 wg x 512 thr) ----
    gemm_qg_256<<<dim3(512), dim3(512), 0, stream>>>(
        (const bf16_t*)hbf, (const bf16_t*)btQG, qkv, gbuf);
    // ---- q/k norm + rope (in place) ----
    norm_rope<<<dim3(B_ * S_), dim3(256), 0, stream>>>(qkv, positions, q_norm_w, k_norm_w);

    // ---- attention: 3-pass chunked scan ----
    chunk_kv<<<dim3(B_ * NH * NC), dim3(256), 0, stream>>>(qkv, wbuf);
    state_scan<<<dim3(B_ * NH * 16), dim3(256), 0, stream>>>(wbuf, rstate, stbuf);
    chunk_out<<<dim3(B_ * NH * NC), dim3(256), 0, stream>>>(qkv, stbuf, obuf);

    // ---- group norm + gate ----
    gnorm_gate<<<dim3(MR * GROUPS_), dim3(256), 0, stream>>>(obuf, gbuf, g_norm_w);
    // ---- output projection (fp32 out) ----
    gemm_mfma<float><<<dim3((MR / 128) * (HID / 128)), dim3(256), 0, stream>>>(
        (const bf16_t*)gbuf, (const bf16_t*)wdT, out, MR, HID, HID);
}

// Round 4
// 436.523 us; speedup vs baseline: 1.1269x; 1.0515x over previous
//
#include <hip/hip_runtime.h>
#include <hip/hip_bf16.h>
#include <math.h>

// ---- problem constants ----
#define NH   16
#define HD   128
#define HID  2048
#define NKV  6144      // 3*NH*HD
#define B_   2
#define S_   2048
#define NC   32        // S/CHUNK
#define CHUNK_ 64
#define GROUPS_ 8

typedef __bf16 bf16_t;
typedef bf16_t bf16x8 __attribute__((ext_vector_type(8)));
typedef float  f32x4  __attribute__((ext_vector_type(4)));

__device__ __forceinline__ float b2f(unsigned int u) {
    union { unsigned int u; float f; } c; c.u = (u & 0xffffu) << 16; return c.f;
}
__device__ __forceinline__ unsigned int f2b(float f) {
    union { float f; unsigned int u; } c; c.f = f;
    unsigned int u = c.u;
    return (u + 0x7fffu + ((u >> 16) & 1u)) >> 16;
}

#define GLOAD_LDS16(gp, lp) __builtin_amdgcn_global_load_lds(                     \
    (const __attribute__((address_space(1))) void*)(gp),                          \
    (__attribute__((address_space(3))) void*)(lp), 16, 0, 0)

// ---------------- fp32 -> bf16 elementwise (8 elems/thread) ----------------
__global__ __launch_bounds__(256) void cvt_bf16(const float* __restrict__ in,
                                                unsigned short* __restrict__ out, int n8)
{
    int i = blockIdx.x * 256 + threadIdx.x;
    if (i >= n8) return;
    const float4* p = (const float4*)in + (size_t)i * 2;
    float4 a = p[0], b = p[1];
    uint4 o;
    o.x = f2b(a.x) | (f2b(a.y) << 16);
    o.y = f2b(a.z) | (f2b(a.w) << 16);
    o.z = f2b(b.x) | (f2b(b.y) << 16);
    o.w = f2b(b.z) | (f2b(b.w) << 16);
    ((uint4*)out)[i] = o;
}

// ------------- fp32 [K][N] -> bf16 [N][K] transpose (32x32 tiles) ---------------
__global__ __launch_bounds__(256) void transpose_cvt(const float* __restrict__ in,
                                                     unsigned short* __restrict__ out,
                                                     int Kdim, int Ndim)
{
    __shared__ float tile[32][33];
    int ntx = Ndim >> 5;
    int bx = blockIdx.x % ntx;
    int by = blockIdx.x / ntx;
    int lx = threadIdx.x & 31, ly = threadIdx.x >> 5;
    int r0 = by * 32, c0 = bx * 32;
    #pragma unroll
    for (int r = 0; r < 4; ++r)
        tile[ly + r * 8][lx] = in[(size_t)(r0 + ly + r * 8) * Ndim + c0 + lx];
    __syncthreads();
    #pragma unroll
    for (int r = 0; r < 4; ++r)
        out[(size_t)(c0 + ly + r * 8) * Kdim + r0 + lx] = (unsigned short)f2b(tile[lx][ly + r * 8]);
}

// ------------- fp32 [K][N] -> packed MFMA-B-frag chunks (for reg-direct B) ------
// Chunk (n16, kb) = 16 n-cols x 32 k: 512 elems (1024 B), laid lane-major so a
// wave's bf16x8 frag load (lane*8) is one fully-coalesced 1KB read.
// elem(n,k) -> chunk n16=n>>4, kb=k>>5, pos (quad*16+l16)*8+e, quad=(k>>3)&3,
// l16=n&15, e=k&7.  Chunk index = n16*64 + kb (Kdim fixed 2048 -> 64 kb's).
__global__ __launch_bounds__(256) void pack_b(const float* __restrict__ in,
                                              unsigned short* __restrict__ out, int Ndim)
{
    __shared__ float tile[32][33];
    int ntx = Ndim >> 5;
    int bx = blockIdx.x % ntx;   // n-tile
    int by = blockIdx.x / ntx;   // k-tile (== kb)
    int lx = threadIdx.x & 31, ly = threadIdx.x >> 5;
    int r0 = by * 32, c0 = bx * 32;
    #pragma unroll
    for (int r = 0; r < 4; ++r)
        tile[ly + r * 8][lx] = in[(size_t)(r0 + ly + r * 8) * Ndim + c0 + lx];
    __syncthreads();
    int quad = (lx >> 3) & 3;    // (k>>3)&3
    int e    = lx & 7;           // k&7
    #pragma unroll
    for (int r = 0; r < 4; ++r) {
        int n = c0 + ly + r * 8;
        int n16 = n >> 4, l16 = n & 15;
        out[((size_t)(n16 * 64 + by) << 9) + (quad * 16 + l16) * 8 + e] =
            (unsigned short)f2b(tile[lx][ly + r * 8]);
    }
}

// ================= 256x256 GEMM, A via LDS + B via registers =================
// v4: B never touches LDS. Each wave loads its 8 B-frags (bf16x8) straight
// from the packed layout (1KB coalesced per load), depth-1 ping-pong across
// tiles: tile t issues B(t+1) into the other array at tile start (registers
// have no cross-wave WAR -> no barrier coupling; vmcnt(0) at tile end gives
// a full-tile in-flight window). A stays LDS-staged (4x wave amplification).
// LDS reads drop 24->16/wave; B stage-writes gone; post-barrier read burst
// halves. A-h1 frags reuse af[] (reload mid-tile under quads(0,*) MFMA).

__device__ __forceinline__ void ld_fr4(bf16x8 (&d)[4][2], const bf16_t* b, int s0, int ri) {
    #pragma unroll
    for (int i = 0; i < 4; ++i)
        #pragma unroll
        for (int k = 0; k < 2; ++k)
            d[i][k] = *(const bf16x8*)(b + (((s0 + i) * 2 + k) << 9) + ri);
}
__device__ __forceinline__ void mfma_quad(f32x4 (&a)[4][2], const bf16x8 (&af)[4][2],
                                          const bf16x8 (&bv)[2][2]) {
    #pragma unroll
    for (int mt = 0; mt < 4; ++mt)
        #pragma unroll
        for (int nt = 0; nt < 2; ++nt)
            #pragma unroll
            for (int ks = 0; ks < 2; ++ks)
                a[mt][nt] = __builtin_amdgcn_mfma_f32_16x16x32_bf16(af[mt][ks], bv[nt][ks], a[mt][nt], 0, 0, 0);
}
// load the wave's 8 B-frags for K-tile tt from packed layout
__device__ __forceinline__ void load_bfrag(bf16x8 (&d)[2][2][2], const bf16_t* Bp,
                                           int n16b, int tt, int lane8) {
    #pragma unroll
    for (int nh = 0; nh < 2; ++nh)
        #pragma unroll
        for (int nt = 0; nt < 2; ++nt)
            #pragma unroll
            for (int ks = 0; ks < 2; ++ks)
                d[nh][nt][ks] = *(const bf16x8*)(Bp +
                    ((size_t)((n16b + nh * 8 + nt) * 64 + tt * 2 + ks) << 9) + lane8);
}

#define BAR()     asm volatile("s_barrier" ::: "memory")
#define VMCNT0()  asm volatile("s_waitcnt vmcnt(0)" ::: "memory")

__global__ __launch_bounds__(512, 2) void gemm_qg_256(const bf16_t* __restrict__ A,
                                                      const bf16_t* __restrict__ Bp,
                                                      unsigned short* __restrict__ Cq,
                                                      unsigned short* __restrict__ Cg)
{
    __shared__ bf16_t Asm[2][2][8192];   // [buf][half][128*64] — A only, 64 KiB
    const int K  = HID;       // 2048
    const int NT = K / 64;    // 32 K-tiles

    int tid  = threadIdx.x;
    int wave = tid >> 6, lane = tid & 63;
    int wm = wave >> 2, wn = wave & 3;            // 2 M-waves x 4 N-waves
    int l16 = lane & 15, quad = lane >> 4;
    int wm4 = wm * 4;
    int lane8 = lane * 8;

    // XCD-aware mapping: each XCD owns an 8x8 (by,bx) tile block (bijective).
    int bid = blockIdx.x;
    int xcd = bid & 7, idx = bid >> 3;
    int by  = (xcd >> 2) * 8 + (idx >> 3);        // 0..15
    int bx  = (xcd & 3) * 8 + (idx & 7);          // 0..31

    int n16b = bx * 16 + wn * 2;                  // packed-B chunk base for this wave

    // swizzled within-subtile read offset (elems): row l16, col quad*8
    int rd_in = ((l16 << 5) | (quad << 3)) ^ (((l16 >> 3) & 1) << 4);

    // pre-swizzled global source decode for global_load_lds
    int ch = lane ^ ((lane & 32) >> 4);
    int rr = ch >> 2;
    int cc = (ch & 3) * 8;

    const bf16_t* aSrc0 = A + (size_t)(by * 256 +       wave * 16 + rr) * K + cc;
    const bf16_t* aSrc1 = A + (size_t)(by * 256 + 128 + wave * 16 + rr) * K + cc;

#define STAGE_A(h, t) do {                                                        \
        const bf16_t* _g = ((h) ? aSrc1 : aSrc0) + (size_t)(t) * 64;              \
        bf16_t* _l = &Asm[(t) & 1][(h)][wave * 1024 + lane * 8];                  \
        GLOAD_LDS16(_g,      _l);                                                 \
        GLOAD_LDS16(_g + 32, _l + 512); } while (0)

    f32x4 acc[2][2][4][2];
    #pragma unroll
    for (int a0 = 0; a0 < 2; ++a0)
        #pragma unroll
        for (int a1 = 0; a1 < 2; ++a1)
            #pragma unroll
            for (int a2 = 0; a2 < 4; ++a2)
                #pragma unroll
                for (int a3 = 0; a3 < 2; ++a3) { f32x4 z = {0.f,0.f,0.f,0.f}; acc[a0][a1][a2][a3] = z; }

    bf16x8 af[4][2];            // A frags (reloaded per half)
    bf16x8 bfA[2][2][2], bfB[2][2][2];   // B frag ping-pong (even/odd tiles)

    // ---- prologue ----
    load_bfrag(bfA, Bp, n16b, 0, lane8);
    STAGE_A(0, 0); STAGE_A(1, 0);
    VMCNT0();
    BAR();

// tile body: consume BFC, load B(t+1) into BFN, stage A(t+1), one barrier.
#define QG_TILE(t, BFC, BFN) do {                                                 \
        const int buf_ = (t) & 1;                                                 \
        load_bfrag(BFN, Bp, n16b, (t) + 1, lane8);                                \
        STAGE_A(0, (t) + 1); STAGE_A(1, (t) + 1);                                 \
        ld_fr4(af, &Asm[buf_][0][0], wm4, rd_in);                                 \
        mfma_quad(acc[0][0], af, BFC[0]);                                         \
        mfma_quad(acc[0][1], af, BFC[1]);                                         \
        ld_fr4(af, &Asm[buf_][1][0], wm4, rd_in);                                 \
        mfma_quad(acc[1][1], af, BFC[1]);                                         \
        mfma_quad(acc[1][0], af, BFC[0]);                                         \
        VMCNT0();                                                                 \
        BAR(); } while (0)

    for (int t = 0; t < NT - 2; t += 2) {        // tiles 0..29
        QG_TILE(t,     bfA, bfB);
        QG_TILE(t + 1, bfB, bfA);
    }
    QG_TILE(NT - 2, bfA, bfB);                   // tile 30 (loads B(31), stages A(31))
    {   // tile 31: pure compute
        ld_fr4(af, &Asm[1][0][0], wm4, rd_in);
        mfma_quad(acc[0][0], af, bfB[0]);
        mfma_quad(acc[0][1], af, bfB[1]);
        ld_fr4(af, &Asm[1][1][0], wm4, rd_in);
        mfma_quad(acc[1][1], af, bfB[1]);
        mfma_quad(acc[1][0], af, bfB[0]);
    }
#undef QG_TILE
#undef STAGE_A

    // ---- epilogue: route cols [0,6144)->Cq, [6144,8192)->Cg (256 | 6144) ----
    unsigned short* Cc; int Nn, colbase;
    if (bx < 24) { Cc = Cq; Nn = NKV; colbase = bx * 256; }
    else         { Cc = Cg; Nn = HID; colbase = bx * 256 - NKV; }
    int row0 = by * 256 + wm * 64 + quad * 4;
    int col0 = colbase + wn * 32 + l16;
    #pragma unroll
    for (int mh = 0; mh < 2; ++mh)
        #pragma unroll
        for (int nh = 0; nh < 2; ++nh)
            #pragma unroll
            for (int mt = 0; mt < 4; ++mt)
                #pragma unroll
                for (int nt = 0; nt < 2; ++nt) {
                    int col = col0 + nh * 128 + nt * 16;
                    #pragma unroll
                    for (int r = 0; r < 4; ++r) {
                        int row = row0 + mh * 128 + mt * 16 + r;
                        Cc[(size_t)row * Nn + col] = (unsigned short)f2b(acc[mh][nh][mt][nt][r]);
                    }
                }
}

// ============ 128x128 barrier-light out-projection: C = A @ Bt^T, fp32 out ====
// qg-style: BK=32, swizzled 16x32 subtiles, depth-1 prefetch, 1 barrier/tile.
// 4 waves (2Mx2N, 64x64 each), LDS 32KB -> 2 blocks/CU resident (desync covers
// barriers). Replaces the old 2-barrier kernel (8-way LDS read conflicts).
__global__ __launch_bounds__(256, 2) void gemm_out_128(const bf16_t* __restrict__ A,
                                                       const bf16_t* __restrict__ Bt,
                                                       float* __restrict__ C)
{
    __shared__ bf16_t As[2][4096];   // [buf][128*32] in 8 subtiles of [16][32]
    __shared__ bf16_t Bs[2][4096];
    const int K  = HID;              // 2048
    const int NT = K / 32;           // 64 K-tiles

    int tid  = threadIdx.x;
    int wave = tid >> 6, lane = tid & 63;
    int wm2 = wave >> 1, wn2 = wave & 1;          // 2M x 2N waves
    int l16 = lane & 15, quad = lane >> 4;
    int w2 = wave * 2;

    // XCD mapping: 512 wg = 8 XCDs x 64; each XCD an 8x8 (by,bx) block.
    int bid = blockIdx.x;
    int xcd = bid & 7, idx = bid >> 3;
    int by  = (xcd >> 1) * 8 + (idx >> 3);        // 0..31
    int bx  = (xcd & 1) * 8 + (idx & 7);          // 0..15

    int rd_in = ((l16 << 5) | (quad << 3)) ^ (((l16 >> 3) & 1) << 4);
    int ch = lane ^ ((lane & 32) >> 4);
    int rr = ch >> 2;
    int cc = (ch & 3) * 8;

    // wave stages subtiles 2w, 2w+1 of each matrix
    const bf16_t* aSrc = A  + (size_t)(by * 128 + w2 * 16 + rr) * K + cc;
    const bf16_t* bSrc = Bt + (size_t)(bx * 128 + w2 * 16 + rr) * K + cc;

#define OSTAGE(t) do {                                                            \
        const int nb_ = (t) & 1;                                                  \
        const bf16_t* _ga = aSrc + (size_t)(t) * 32;                              \
        const bf16_t* _gb = bSrc + (size_t)(t) * 32;                              \
        GLOAD_LDS16(_ga,                  &As[nb_][w2 * 512 + lane * 8]);         \
        GLOAD_LDS16(_ga + (size_t)16 * K, &As[nb_][w2 * 512 + 512 + lane * 8]);   \
        GLOAD_LDS16(_gb,                  &Bs[nb_][w2 * 512 + lane * 8]);         \
        GLOAD_LDS16(_gb + (size_t)16 * K, &Bs[nb_][w2 * 512 + 512 + lane * 8]); } while (0)

    f32x4 acc[4][4];
    #pragma unroll
    for (int i = 0; i < 4; ++i)
        #pragma unroll
        for (int j = 0; j < 4; ++j) { f32x4 z = {0.f,0.f,0.f,0.f}; acc[i][j] = z; }

#define OCOMP(t) do {                                                             \
        const int b_ = (t) & 1;                                                   \
        bf16x8 af_[4], bf_[4];                                                    \
        _Pragma("unroll")                                                         \
        for (int i = 0; i < 4; ++i)                                               \
            af_[i] = *(const bf16x8*)(&As[b_][((wm2 * 4 + i) << 9) + rd_in]);     \
        _Pragma("unroll")                                                         \
        for (int j = 0; j < 4; ++j)                                               \
            bf_[j] = *(const bf16x8*)(&Bs[b_][((wn2 * 4 + j) << 9) + rd_in]);     \
        _Pragma("unroll")                                                         \
        for (int i = 0; i < 4; ++i)                                               \
            _Pragma("unroll")                                                     \
            for (int j = 0; j < 4; ++j)                                           \
                acc[i][j] = __builtin_amdgcn_mfma_f32_16x16x32_bf16(af_[i], bf_[j], acc[i][j], 0, 0, 0); } while (0)

    OSTAGE(0);
    VMCNT0();
    BAR();
    #pragma unroll 2
    for (int t = 0; t < NT - 1; ++t) {
        OSTAGE(t + 1);
        OCOMP(t);
        VMCNT0();
        BAR();
    }
    OCOMP(NT - 1);
#undef OSTAGE
#undef OCOMP

    #pragma unroll
    for (int i = 0; i < 4; ++i)
        #pragma unroll
        for (int j = 0; j < 4; ++j) {
            int col = bx * 128 + wn2 * 64 + j * 16 + l16;
            #pragma unroll
            for (int r = 0; r < 4; ++r) {
                int row = by * 128 + wm2 * 64 + i * 16 + quad * 4 + r;
                C[(size_t)row * HID + col] = acc[i][j][r];
            }
        }
}

// ------- q/k RMSNorm + partial RoPE, in place. grid = B*S blocks of 256. -------
__global__ __launch_bounds__(256) void norm_rope(unsigned short* __restrict__ qkv,
                                                 const int* __restrict__ positions,
                                                 const float* __restrict__ qw,
                                                 const float* __restrict__ kw)
{
    int bs = blockIdx.x;
    int s  = bs & (S_ - 1);
    int tid = threadIdx.x;
    int l16 = tid & 15;
    unsigned short* base = qkv + (size_t)bs * NKV;
    float pos = (float)positions[s];

    #pragma unroll
    for (int p = 0; p < 2; ++p) {
        int rr = p * 16 + (tid >> 4);   // 0..31
        int qk = rr >> 4;
        int h  = rr & 15;
        unsigned short* row = base + qk * HID + h * HD;
        const float* w = qk ? kw : qw;
        uint4 v = *(const uint4*)(row + l16 * 8);
        float x[8];
        x[0] = b2f(v.x); x[1] = b2f(v.x >> 16);
        x[2] = b2f(v.y); x[3] = b2f(v.y >> 16);
        x[4] = b2f(v.z); x[5] = b2f(v.z >> 16);
        x[6] = b2f(v.w); x[7] = b2f(v.w >> 16);
        float ss = 0.f;
        #pragma unroll
        for (int t = 0; t < 8; ++t) ss += x[t] * x[t];
        ss += __shfl_xor(ss, 1); ss += __shfl_xor(ss, 2);
        ss += __shfl_xor(ss, 4); ss += __shfl_xor(ss, 8);
        float inv = rsqrtf(ss * (1.0f / 128.0f) + 1e-6f);
        float n[8];
        #pragma unroll
        for (int t = 0; t < 8; ++t) n[t] = x[t] * inv * w[l16 * 8 + t];
        float pr[8];
        #pragma unroll
        for (int t = 0; t < 8; ++t) pr[t] = __shfl_xor(n[t], 4);   // dims +-32
        if (l16 < 8) {
            #pragma unroll
            for (int t = 0; t < 8; ++t) {
                int dim = l16 * 8 + t;
                int i = dim & 31;
                float ang = pos * exp2f(-(float)i * 0.4152410118609203f);
                float cs = cosf(ang), sn = sinf(ang);
                n[t] = (dim < 32) ? (n[t] * cs - pr[t] * sn) : (n[t] * cs + pr[t] * sn);
            }
        }
        uint4 o;
        o.x = f2b(n[0]) | (f2b(n[1]) << 16);
        o.y = f2b(n[2]) | (f2b(n[3]) << 16);
        o.z = f2b(n[4]) | (f2b(n[5]) << 16);
        o.w = f2b(n[6]) | (f2b(n[7]) << 16);
        *(uint4*)(row + l16 * 8) = o;
    }
}

// ============ pass 1: per-chunk KV outer product  Wt[e][d] = sum_j kdec_j V[j][e] K[j][d]
__global__ __launch_bounds__(256) void chunk_kv(const unsigned short* __restrict__ qkv,
                                                unsigned short* __restrict__ wbuf)
{
    __shared__ unsigned short kt[128 * 72];   // kt[d][j]
    __shared__ unsigned short vt[128 * 72];   // vt[e][j] * kdec[j]
    int bi = blockIdx.x;
    int c = bi & 31, bh = bi >> 5, h = bh & 15, b = bh >> 4;
    int tid = threadIdx.x;
    float slope = -exp2f(-0.5f * (float)(h + 1)) * (1.0f + 1e-5f);

    const unsigned short* kbase = qkv + ((size_t)(b * S_ + c * CHUNK_)) * NKV + HID + h * HD;
    const unsigned short* vbase = kbase + HID;

    for (int idx = tid; idx < 4096; idx += 256) {
        int j = idx >> 6, p = idx & 63;
        unsigned int ku = *(const unsigned int*)(kbase + (size_t)j * NKV + p * 2);
        kt[(2 * p) * 72 + j]     = (unsigned short)(ku & 0xffffu);
        kt[(2 * p + 1) * 72 + j] = (unsigned short)(ku >> 16);
        float kd = expf(slope * (float)(63 - j));
        unsigned int vu = *(const unsigned int*)(vbase + (size_t)j * NKV + p * 2);
        vt[(2 * p) * 72 + j]     = (unsigned short)f2b(b2f(vu) * kd);
        vt[(2 * p + 1) * 72 + j] = (unsigned short)f2b(b2f(vu >> 16) * kd);
    }
    __syncthreads();

    int lane = tid & 63, wave = tid >> 6;
    int wm = (wave >> 1) * 64;     // e
    int wn = (wave & 1) * 64;      // d
    int l16 = lane & 15, quad = lane >> 4;

    f32x4 acc[4][4];
    #pragma unroll
    for (int i = 0; i < 4; ++i)
        #pragma unroll
        for (int j = 0; j < 4; ++j) { f32x4 z = {0.f,0.f,0.f,0.f}; acc[i][j] = z; }

    #pragma unroll
    for (int ks = 0; ks < 64; ks += 32) {
        bf16x8 af[4], bf[4];
        #pragma unroll
        for (int t = 0; t < 4; ++t) {
            af[t] = *(const bf16x8*)((const bf16_t*)vt + (wm + t * 16 + l16) * 72 + ks + quad * 8);
            bf[t] = *(const bf16x8*)((const bf16_t*)kt + (wn + t * 16 + l16) * 72 + ks + quad * 8);
        }
        #pragma unroll
        for (int mt = 0; mt < 4; ++mt)
            #pragma unroll
            for (int nt = 0; nt < 4; ++nt)
                acc[mt][nt] = __builtin_amdgcn_mfma_f32_16x16x32_bf16(af[mt], bf[nt], acc[mt][nt], 0, 0, 0);
    }

    unsigned short* wp = wbuf + ((size_t)bi << 14);  // [e][d] 128x128
    #pragma unroll
    for (int mt = 0; mt < 4; ++mt)
        #pragma unroll
        for (int nt = 0; nt < 4; ++nt) {
            int dcol = wn + nt * 16 + l16;
            #pragma unroll
            for (int r = 0; r < 4; ++r) {
                int erow = wm + mt * 16 + quad * 4 + r;
                wp[(size_t)erow * 128 + dcol] = (unsigned short)f2b(acc[mt][nt][r]);
            }
        }
}

// ============ pass 2: sequential state scan (linear recurrence), 512 blocks
__global__ __launch_bounds__(256) void state_scan(const unsigned short* __restrict__ wbuf,
                                                  const float* __restrict__ rs0,
                                                  unsigned short* __restrict__ stbuf)
{
    int bi = blockIdx.x;
    int es = bi & 15, bh = bi >> 4, h = bh & 15, b = bh >> 4;
    int tid = threadIdx.x;
    float slope = -exp2f(-0.5f * (float)(h + 1)) * (1.0f + 1e-5f);
    float lam = expf(slope * 64.0f);

    int e  = es * 8 + (tid >> 5);
    int d0 = (tid & 31) * 4;

    float S[4];
    const float* rp = rs0 + ((size_t)(b * NH + h)) * HD * HD + e;   // rstate[b][h][d][e]
    #pragma unroll
    for (int t = 0; t < 4; ++t) S[t] = rp[(size_t)(d0 + t) * HD];

    size_t off = (size_t)e * 128 + d0;
    size_t base = (((size_t)bh * NC) << 14) + off;
    // depth-2 w prefetch: breaks the store->load->update serial chain
    uint2 w0 = *(const uint2*)(wbuf + base);
    uint2 w1 = *(const uint2*)(wbuf + base + (1 << 14));
    for (int c = 0; c < NC; ++c) {
        uint2 o;
        o.x = f2b(S[0]) | (f2b(S[1]) << 16);
        o.y = f2b(S[2]) | (f2b(S[3]) << 16);
        *(uint2*)(stbuf + base) = o;
        uint2 w2 = w1;
        if (c + 2 < NC) w2 = *(const uint2*)(wbuf + base + (2 << 14));
        S[0] = S[0] * lam + b2f(w0.x);
        S[1] = S[1] * lam + b2f(w0.x >> 16);
        S[2] = S[2] * lam + b2f(w0.y);
        S[3] = S[3] * lam + b2f(w0.y >> 16);
        w0 = w1; w1 = w2;
        base += (1 << 14);
    }
}

// ============ pass 3: per-chunk output  O = (mask.QK^T)@V + qdec*(Q@S_prev)
__global__ __launch_bounds__(256) void chunk_out(const unsigned short* __restrict__ qkv,
                                                 const unsigned short* __restrict__ stbuf,
                                                 unsigned short* __restrict__ obuf)
{
    __shared__ unsigned short qs[64 * 136];   // q[i][d]
    __shared__ unsigned short vt[128 * 72];   // v^T[e][j]
    __shared__ unsigned short sc[64 * 72];    // masked scores [i][j]

    int bi = blockIdx.x;
    int c = bi & 31, bh = bi >> 5, h = bh & 15, b = bh >> 4;
    int tid = threadIdx.x;
    float slope = -exp2f(-0.5f * (float)(h + 1)) * (1.0f + 1e-5f);

    int lane = tid & 63, wave = tid >> 6;
    int l16 = lane & 15, quad = lane >> 4;
    int wn3 = wave * 32;

    // ---- prefetch st B-frags into registers FIRST: HBM latency (~900cyc) hides
    //      behind staging + scores + intra phases.
    const unsigned short* stp = stbuf + (((size_t)bh * NC + c) << 14);
    bf16x8 bsf[4][2];
    #pragma unroll
    for (int ksp4 = 0; ksp4 < 4; ++ksp4)
        #pragma unroll
        for (int nt = 0; nt < 2; ++nt)
            bsf[ksp4][nt] = *(const bf16x8*)((const bf16_t*)stp +
                (size_t)(wn3 + nt * 16 + l16) * 128 + ksp4 * 32 + quad * 8);

    const unsigned short* qrow = qkv + ((size_t)(b * S_ + c * CHUNK_)) * NKV + h * HD;
    const unsigned short* krow = qrow + HID;
    // stage q (rows of 128, padded stride 136)
    for (int idx = tid; idx < 1024; idx += 256) {
        int row = idx >> 4, c8 = (idx & 15) * 8;
        *(uint4*)(qs + row * 136 + c8) = *(const uint4*)(qrow + (size_t)row * NKV + c8);
    }
    // stage v transposed
    const unsigned short* vbase = qrow + 2 * HID;
    for (int idx = tid; idx < 4096; idx += 256) {
        int j = idx >> 6, p = idx & 63;
        unsigned int vu = *(const unsigned int*)(vbase + (size_t)j * NKV + p * 2);
        vt[(2 * p) * 72 + j]     = (unsigned short)(vu & 0xffffu);
        vt[(2 * p + 1) * 72 + j] = (unsigned short)(vu >> 16);
    }
    __syncthreads();

    // ---- scores: each wave computes rows [wave*16, +16) x all 64 j; k-frags global ----
    {
        f32x4 accS[4];
        #pragma unroll
        for (int t = 0; t < 4; ++t) { f32x4 z = {0.f,0.f,0.f,0.f}; accS[t] = z; }
        #pragma unroll
        for (int ksp = 0; ksp < 128; ksp += 32) {
            bf16x8 aq = *(const bf16x8*)((const bf16_t*)qs + (wave * 16 + l16) * 136 + ksp + quad * 8);
            #pragma unroll
            for (int nt = 0; nt < 4; ++nt) {
                bf16x8 bk = *(const bf16x8*)((const bf16_t*)krow + (size_t)(nt * 16 + l16) * NKV + ksp + quad * 8);
                accS[nt] = __builtin_amdgcn_mfma_f32_16x16x32_bf16(aq, bk, accS[nt], 0, 0, 0);
            }
        }
        float ad[4];
        #pragma unroll
        for (int r = 0; r < 4; ++r) ad[r] = expf(slope * (float)(wave * 16 + quad * 4 + r));
        #pragma unroll
        for (int nt = 0; nt < 4; ++nt) {
            int j = nt * 16 + l16;
            float bd = expf(-slope * (float)j);
            #pragma unroll
            for (int r = 0; r < 4; ++r) {
                int i = wave * 16 + quad * 4 + r;
                float v = (i >= j) ? accS[nt][r] * ad[r] * bd : 0.0f;
                sc[i * 72 + j] = (unsigned short)f2b(v);
            }
        }
    }
    __syncthreads();

    f32x4 accI[4][2], accE[4][2];
    #pragma unroll
    for (int i = 0; i < 4; ++i)
        #pragma unroll
        for (int j = 0; j < 2; ++j) { f32x4 z = {0.f,0.f,0.f,0.f}; accI[i][j] = z; accE[i][j] = z; }

    // intra: K = 64 (j)
    #pragma unroll
    for (int ksp = 0; ksp < 64; ksp += 32) {
        bf16x8 as[4], bv[2];
        #pragma unroll
        for (int mt = 0; mt < 4; ++mt)
            as[mt] = *(const bf16x8*)((const bf16_t*)sc + (mt * 16 + l16) * 72 + ksp + quad * 8);
        #pragma unroll
        for (int nt = 0; nt < 2; ++nt)
            bv[nt] = *(const bf16x8*)((const bf16_t*)vt + (wn3 + nt * 16 + l16) * 72 + ksp + quad * 8);
        #pragma unroll
        for (int mt = 0; mt < 4; ++mt)
            #pragma unroll
            for (int nt = 0; nt < 2; ++nt)
                accI[mt][nt] = __builtin_amdgcn_mfma_f32_16x16x32_bf16(as[mt], bv[nt], accI[mt][nt], 0, 0, 0);
    }
    // inter: K = 128 (d), B-frags already in registers (bsf)
    #pragma unroll
    for (int ksp4 = 0; ksp4 < 4; ++ksp4) {
        bf16x8 aq[4];
        #pragma unroll
        for (int mt = 0; mt < 4; ++mt)
            aq[mt] = *(const bf16x8*)((const bf16_t*)qs + (mt * 16 + l16) * 136 + ksp4 * 32 + quad * 8);
        #pragma unroll
        for (int mt = 0; mt < 4; ++mt)
            #pragma unroll
            for (int nt = 0; nt < 2; ++nt)
                accE[mt][nt] = __builtin_amdgcn_mfma_f32_16x16x32_bf16(aq[mt], bsf[ksp4][nt], accE[mt][nt], 0, 0, 0);
    }

    // epilogue: O = accI + qdec[i]*accE, bf16 store
    #pragma unroll
    for (int mt = 0; mt < 4; ++mt) {
        #pragma unroll
        for (int r = 0; r < 4; ++r) {
            int i = mt * 16 + quad * 4 + r;
            float qd = expf(slope * (float)(i + 1));
            int orow = b * S_ + c * CHUNK_ + i;
            #pragma unroll
            for (int nt = 0; nt < 2; ++nt) {
                int col = h * HD + wn3 + nt * 16 + l16;
                float o = accI[mt][nt][r] + qd * accE[mt][nt][r];
                obuf[(size_t)orow * 2048 + col] = (unsigned short)f2b(o);
            }
        }
    }
}

// ------- group RMSNorm + sigmoid gate: read o bf16 + gate bf16, write bf16 -------
__global__ __launch_bounds__(256) void gnorm_gate(const unsigned short* __restrict__ o,
                                                  unsigned short* __restrict__ gate,
                                                  const float* __restrict__ gw)
{
    int row = blockIdx.x >> 3;
    int g   = blockIdx.x & 7;
    int col = g * 256 + threadIdx.x;
    size_t idx = (size_t)row * 2048 + col;
    float ov = b2f(o[idx]);
    float ss = ov * ov;
    #pragma unroll
    for (int off = 32; off > 0; off >>= 1) ss += __shfl_xor(ss, off);
    __shared__ float part[4];
    if ((threadIdx.x & 63) == 0) part[threadIdx.x >> 6] = ss;
    __syncthreads();
    float tot = part[0] + part[1] + part[2] + part[3];
    float inv = rsqrtf(tot * (1.0f / 256.0f) + 1e-6f);
    float gv = b2f(gate[idx]);
    float sig = 1.0f / (1.0f + expf(-gv));
    gate[idx] = (unsigned short)f2b(ov * inv * gw[col] * sig);
}

// ---------------- launch ----------------
extern "C" void kernel_launch(void* const* d_in, const int* in_sizes, int n_in,
                              void* d_out, int out_size, void* d_ws, size_t ws_size,
                              hipStream_t stream) {
    const int*   positions = (const int*)d_in[0];
    const float* hidden    = (const float*)d_in[1];
    const float* rstate    = (const float*)d_in[2];
    const float* w_qkv     = (const float*)d_in[3];
    const float* w_g       = (const float*)d_in[4];
    const float* w_dense   = (const float*)d_in[5];
    const float* q_norm_w  = (const float*)d_in[6];
    const float* k_norm_w  = (const float*)d_in[7];
    const float* g_norm_w  = (const float*)d_in[8];
    float* out = (float*)d_out;

    const int MR = B_ * S_;  // 4096

    // ---- ws layout (total 159,383,552 B — unchanged) ----
    char* w = (char*)d_ws;
    unsigned short* qkv  = (unsigned short*)w;            w += (size_t)MR * NKV * 2;     // 50.3 MB
    unsigned short* gbuf = (unsigned short*)w;            w += (size_t)MR * 2048 * 2;    // 16.8 MB
    unsigned short* wdT  = (unsigned short*)w;            w += (size_t)HID * HID * 2;    // 8.4 MB
    char* regionA = w;                                    w += (size_t)MR * HID * 2 + (size_t)8192 * HID * 2; // 50.3 MB
    char* regionB = w;                                    // 33.6 MB
    unsigned short* hbf   = (unsigned short*)regionA;                                 // 16.8 MB
    unsigned short* Bp    = (unsigned short*)(regionA + (size_t)MR * HID * 2);        // packed B: 512x64 chunks = 33.5 MB
    unsigned short* stbuf = (unsigned short*)regionA;     // 32 MB, after GEMMs
    unsigned short* wbuf  = (unsigned short*)regionB;     // 32 MB
    unsigned short* obuf  = (unsigned short*)regionB;     // 16.8 MB, after pass2

    // ---- conversions ----
    cvt_bf16<<<dim3((MR * HID / 8 + 255) / 256), dim3(256), 0, stream>>>(hidden, hbf, MR * HID / 8);
    // pack w_qkv (cols 0..6143 -> n16 0..383) and w_g (-> n16 384..511)
    pack_b<<<dim3((HID / 32) * (NKV / 32)), dim3(256), 0, stream>>>(w_qkv, Bp, NKV);
    pack_b<<<dim3((HID / 32) * (HID / 32)), dim3(256), 0, stream>>>(w_g, Bp + (size_t)384 * 64 * 512, HID);
    transpose_cvt<<<dim3((HID / 32) * (HID / 32)), dim3(256), 0, stream>>>(w_dense, wdT, HID, HID);

    // ---- fused qkv+gate projection: 256^2, A-LDS + B-reg (512 wg x 512 thr) ----
    gemm_qg_256<<<dim3(512), dim3(512), 0, stream>>>(
        (const bf16_t*)hbf, (const bf16_t*)Bp, qkv, gbuf);
    // ---- q/k norm + rope (in place) ----
    norm_rope<<<dim3(B_ * S_), dim3(256), 0, stream>>>(qkv, positions, q_norm_w, k_norm_w);

    // ---- attention: 3-pass chunked scan ----
    chunk_kv<<<dim3(B_ * NH * NC), dim3(256), 0, stream>>>(qkv, wbuf);
    state_scan<<<dim3(B_ * NH * 16), dim3(256), 0, stream>>>(wbuf, rstate, stbuf);
    chunk_out<<<dim3(B_ * NH * NC), dim3(256), 0, stream>>>(qkv, stbuf, obuf);

    // ---- group norm + gate ----
    gnorm_gate<<<dim3(MR * GROUPS_), dim3(256), 0, stream>>>(obuf, gbuf, g_norm_w);
    // ---- output projection (fp32 out), barrier-light 128^2 ----
    gemm_out_128<<<dim3(512), dim3(256), 0, stream>>>(
        (const bf16_t*)gbuf, (const bf16_t*)wdT, out);
}

// Round 5
// 424.097 us; speedup vs baseline: 1.1599x; 1.0293x over previous
//
#include <hip/hip_runtime.h>
#include <hip/hip_bf16.h>
#include <math.h>

// ---- problem constants ----
#define NH   16
#define HD   128
#define HID  2048
#define NKV  6144      // 3*NH*HD
#define B_   2
#define S_   2048
#define NC   32        // S/CHUNK
#define CHUNK_ 64
#define GROUPS_ 8

typedef __bf16 bf16_t;
typedef bf16_t bf16x8 __attribute__((ext_vector_type(8)));
typedef float  f32x4  __attribute__((ext_vector_type(4)));

__device__ __forceinline__ float b2f(unsigned int u) {
    union { unsigned int u; float f; } c; c.u = (u & 0xffffu) << 16; return c.f;
}
__device__ __forceinline__ unsigned int f2b(float f) {
    union { float f; unsigned int u; } c; c.f = f;
    unsigned int u = c.u;
    return (u + 0x7fffu + ((u >> 16) & 1u)) >> 16;
}

#define GLOAD_LDS16(gp, lp) __builtin_amdgcn_global_load_lds(                     \
    (const __attribute__((address_space(1))) void*)(gp),                          \
    (__attribute__((address_space(3))) void*)(lp), 16, 0, 0)

// ---------------- fp32 -> bf16 elementwise (8 elems/thread) ----------------
__global__ __launch_bounds__(256) void cvt_bf16(const float* __restrict__ in,
                                                unsigned short* __restrict__ out, int n8)
{
    int i = blockIdx.x * 256 + threadIdx.x;
    if (i >= n8) return;
    const float4* p = (const float4*)in + (size_t)i * 2;
    float4 a = p[0], b = p[1];
    uint4 o;
    o.x = f2b(a.x) | (f2b(a.y) << 16);
    o.y = f2b(a.z) | (f2b(a.w) << 16);
    o.z = f2b(b.x) | (f2b(b.y) << 16);
    o.w = f2b(b.z) | (f2b(b.w) << 16);
    ((uint4*)out)[i] = o;
}

// ------------- fp32 [K][N] -> bf16 [N][K] transpose (32x32 tiles) ---------------
__global__ __launch_bounds__(256) void transpose_cvt(const float* __restrict__ in,
                                                     unsigned short* __restrict__ out,
                                                     int Kdim, int Ndim)
{
    __shared__ float tile[32][33];
    int ntx = Ndim >> 5;
    int bx = blockIdx.x % ntx;
    int by = blockIdx.x / ntx;
    int lx = threadIdx.x & 31, ly = threadIdx.x >> 5;
    int r0 = by * 32, c0 = bx * 32;
    #pragma unroll
    for (int r = 0; r < 4; ++r)
        tile[ly + r * 8][lx] = in[(size_t)(r0 + ly + r * 8) * Ndim + c0 + lx];
    __syncthreads();
    #pragma unroll
    for (int r = 0; r < 4; ++r)
        out[(size_t)(c0 + ly + r * 8) * Kdim + r0 + lx] = (unsigned short)f2b(tile[lx][ly + r * 8]);
}

// ================= 256x256 barrier-light GEMM (qkv+gate fused) ===============
// v3 (round-3 proven, 118.5us / MfmaUtil 52.6): depth-1 prefetch -> ONE
// barrier per K-tile, zero intra-tile barriers. Both A and B LDS-staged:
// LDS-staged operands drain incrementally under MFMA via counted lgkmcnt
// (round-4 lesson: register-B drains monolithically via vmcnt -> regressed).
// Tile t stages t+1 into nbuf (writes) while frag reads hit buf (disjoint);
// one vmcnt(0)+s_barrier per tile; stage loads issued a full tile (~2300cyc)
// before the wait -> HBM latency fully hidden.

__device__ __forceinline__ void ld_fr4(bf16x8 (&d)[4][2], const bf16_t* b, int s0, int ri) {
    #pragma unroll
    for (int i = 0; i < 4; ++i)
        #pragma unroll
        for (int k = 0; k < 2; ++k)
            d[i][k] = *(const bf16x8*)(b + (((s0 + i) * 2 + k) << 9) + ri);
}
__device__ __forceinline__ void ld_fr2(bf16x8 (&d)[2][2], const bf16_t* b, int s0, int ri) {
    #pragma unroll
    for (int i = 0; i < 2; ++i)
        #pragma unroll
        for (int k = 0; k < 2; ++k)
            d[i][k] = *(const bf16x8*)(b + (((s0 + i) * 2 + k) << 9) + ri);
}
__device__ __forceinline__ void mfma_quad(f32x4 (&a)[4][2], const bf16x8 (&af)[4][2],
                                          const bf16x8 (&bv)[2][2]) {
    #pragma unroll
    for (int mt = 0; mt < 4; ++mt)
        #pragma unroll
        for (int nt = 0; nt < 2; ++nt)
            #pragma unroll
            for (int ks = 0; ks < 2; ++ks)
                a[mt][nt] = __builtin_amdgcn_mfma_f32_16x16x32_bf16(af[mt][ks], bv[nt][ks], a[mt][nt], 0, 0, 0);
}

#define BAR()     asm volatile("s_barrier" ::: "memory")
#define VMCNT0()  asm volatile("s_waitcnt vmcnt(0)" ::: "memory")

__global__ __launch_bounds__(512, 2) void gemm_qg_256(const bf16_t* __restrict__ A,
                                                      const bf16_t* __restrict__ Bt,
                                                      unsigned short* __restrict__ Cq,
                                                      unsigned short* __restrict__ Cg)
{
    __shared__ bf16_t Asm[2][2][8192];   // [buf][half][128*64]
    __shared__ bf16_t Bsm[2][2][8192];
    const int K  = HID;       // 2048
    const int NT = K / 64;    // 32 K-tiles

    int tid  = threadIdx.x;
    int wave = tid >> 6, lane = tid & 63;
    int wm = wave >> 2, wn = wave & 3;            // 2 M-waves x 4 N-waves
    int l16 = lane & 15, quad = lane >> 4;
    int wm4 = wm * 4, wn2 = wn * 2;

    // XCD-aware mapping: each XCD (bid&7) owns an 8x8 (by,bx) tile block ->
    // ~8.4MB A + 8.4MB B per XCD. 512 = 8*64 exact -> bijective.
    int bid = blockIdx.x;
    int xcd = bid & 7, idx = bid >> 3;            // idx in 0..63
    int by  = (xcd >> 2) * 8 + (idx >> 3);        // 0..15
    int bx  = (xcd & 3) * 8 + (idx & 7);          // 0..31

    // swizzled within-subtile read offset (elems): row l16, col quad*8
    int rd_in = ((l16 << 5) | (quad << 3)) ^ (((l16 >> 3) & 1) << 4);

    // pre-swizzled global source decode for global_load_lds (one subtile/instr)
    int ch = lane ^ ((lane & 32) >> 4);
    int rr = ch >> 2;            // row within 16-row subtile
    int cc = (ch & 3) * 8;       // col (elems) within 32-col subtile

    // wave stages subtile row-block R=wave (C=0,1) of each half-tile
    const bf16_t* aSrc0 = A  + (size_t)(by * 256 +       wave * 16 + rr) * K + cc;
    const bf16_t* aSrc1 = A  + (size_t)(by * 256 + 128 + wave * 16 + rr) * K + cc;
    const bf16_t* bSrc0 = Bt + (size_t)(bx * 256 +       wave * 16 + rr) * K + cc;
    const bf16_t* bSrc1 = Bt + (size_t)(bx * 256 + 128 + wave * 16 + rr) * K + cc;

#define STAGE_A(h, t) do {                                                        \
        const bf16_t* _g = ((h) ? aSrc1 : aSrc0) + (size_t)(t) * 64;              \
        bf16_t* _l = &Asm[(t) & 1][(h)][wave * 1024 + lane * 8];                  \
        GLOAD_LDS16(_g,      _l);                                                 \
        GLOAD_LDS16(_g + 32, _l + 512); } while (0)
#define STAGE_B(h, t) do {                                                        \
        const bf16_t* _g = ((h) ? bSrc1 : bSrc0) + (size_t)(t) * 64;              \
        bf16_t* _l = &Bsm[(t) & 1][(h)][wave * 1024 + lane * 8];                  \
        GLOAD_LDS16(_g,      _l);                                                 \
        GLOAD_LDS16(_g + 32, _l + 512); } while (0)

    f32x4 acc[2][2][4][2];
    #pragma unroll
    for (int a0 = 0; a0 < 2; ++a0)
        #pragma unroll
        for (int a1 = 0; a1 < 2; ++a1)
            #pragma unroll
            for (int a2 = 0; a2 < 4; ++a2)
                #pragma unroll
                for (int a3 = 0; a3 < 2; ++a3) { f32x4 z = {0.f,0.f,0.f,0.f}; acc[a0][a1][a2][a3] = z; }

    // ---- prologue: stage tile 0, drain, sync ----
    STAGE_A(0, 0); STAGE_B(0, 0); STAGE_A(1, 0); STAGE_B(1, 0);
    VMCNT0();
    BAR();

    // ---- main loop: one barrier per K-tile; reads buf, stages nbuf ----
    #pragma unroll 2
    for (int t = 0; t < NT - 1; ++t) {
        const int buf = t & 1;
        // prefetch next tile (writes nbuf only; disjoint from this tile's reads)
        STAGE_A(0, t + 1); STAGE_B(0, t + 1); STAGE_A(1, t + 1); STAGE_B(1, t + 1);
        // compute tile t: compiler free to interleave ds_read and MFMA with
        // counted lgkmcnt; no intra-tile barriers.
        {
            bf16x8 afA[4][2], afB[4][2], bf0[2][2], bf1[2][2];
            ld_fr4(afA, &Asm[buf][0][0], wm4, rd_in);
            ld_fr2(bf0, &Bsm[buf][0][0], wn2, rd_in);
            mfma_quad(acc[0][0], afA, bf0);
            ld_fr2(bf1, &Bsm[buf][1][0], wn2, rd_in);
            mfma_quad(acc[0][1], afA, bf1);
            ld_fr4(afB, &Asm[buf][1][0], wm4, rd_in);
            mfma_quad(acc[1][1], afB, bf1);
            mfma_quad(acc[1][0], afB, bf0);
        }
        VMCNT0();   // stage loads issued a full tile ago -> latency already hidden
        BAR();
    }
    // ---- tail tile NT-1: pure compute ----
    {
        const int buf = (NT - 1) & 1;
        bf16x8 afA[4][2], afB[4][2], bf0[2][2], bf1[2][2];
        ld_fr4(afA, &Asm[buf][0][0], wm4, rd_in);
        ld_fr2(bf0, &Bsm[buf][0][0], wn2, rd_in);
        mfma_quad(acc[0][0], afA, bf0);
        ld_fr2(bf1, &Bsm[buf][1][0], wn2, rd_in);
        mfma_quad(acc[0][1], afA, bf1);
        ld_fr4(afB, &Asm[buf][1][0], wm4, rd_in);
        mfma_quad(acc[1][1], afB, bf1);
        mfma_quad(acc[1][0], afB, bf0);
    }
#undef STAGE_A
#undef STAGE_B

    // ---- epilogue: route cols [0,6144)->Cq, [6144,8192)->Cg (256 | 6144) ----
    unsigned short* Cc; int Nn, colbase;
    if (bx < 24) { Cc = Cq; Nn = NKV; colbase = bx * 256; }
    else         { Cc = Cg; Nn = HID; colbase = bx * 256 - NKV; }
    int row0 = by * 256 + wm * 64 + quad * 4;
    int col0 = colbase + wn * 32 + l16;
    #pragma unroll
    for (int mh = 0; mh < 2; ++mh)
        #pragma unroll
        for (int nh = 0; nh < 2; ++nh)
            #pragma unroll
            for (int mt = 0; mt < 4; ++mt)
                #pragma unroll
                for (int nt = 0; nt < 2; ++nt) {
                    int col = col0 + nh * 128 + nt * 16;
                    #pragma unroll
                    for (int r = 0; r < 4; ++r) {
                        int row = row0 + mh * 128 + mt * 16 + r;
                        Cc[(size_t)row * Nn + col] = (unsigned short)f2b(acc[mh][nh][mt][nt][r]);
                    }
                }
}

// ============ 128x128 barrier-light out-projection: C = A @ Bt^T, fp32 out ====
// qg-style: BK=32, swizzled 16x32 subtiles, depth-1 prefetch, 1 barrier/tile.
// 4 waves (2Mx2N, 64x64 each), LDS 32KB -> 2 blocks/CU resident.
__global__ __launch_bounds__(256, 2) void gemm_out_128(const bf16_t* __restrict__ A,
                                                       const bf16_t* __restrict__ Bt,
                                                       float* __restrict__ C)
{
    __shared__ bf16_t As[2][4096];   // [buf][128*32] in 8 subtiles of [16][32]
    __shared__ bf16_t Bs[2][4096];
    const int K  = HID;              // 2048
    const int NT = K / 32;           // 64 K-tiles

    int tid  = threadIdx.x;
    int wave = tid >> 6, lane = tid & 63;
    int wm2 = wave >> 1, wn2 = wave & 1;          // 2M x 2N waves
    int l16 = lane & 15, quad = lane >> 4;
    int w2 = wave * 2;

    // XCD mapping: 512 wg = 8 XCDs x 64; each XCD an 8x8 (by,bx) block.
    int bid = blockIdx.x;
    int xcd = bid & 7, idx = bid >> 3;
    int by  = (xcd >> 1) * 8 + (idx >> 3);        // 0..31
    int bx  = (xcd & 1) * 8 + (idx & 7);          // 0..15

    int rd_in = ((l16 << 5) | (quad << 3)) ^ (((l16 >> 3) & 1) << 4);
    int ch = lane ^ ((lane & 32) >> 4);
    int rr = ch >> 2;
    int cc = (ch & 3) * 8;

    // wave stages subtiles 2w, 2w+1 of each matrix
    const bf16_t* aSrc = A  + (size_t)(by * 128 + w2 * 16 + rr) * K + cc;
    const bf16_t* bSrc = Bt + (size_t)(bx * 128 + w2 * 16 + rr) * K + cc;

#define OSTAGE(t) do {                                                            \
        const int nb_ = (t) & 1;                                                  \
        const bf16_t* _ga = aSrc + (size_t)(t) * 32;                              \
        const bf16_t* _gb = bSrc + (size_t)(t) * 32;                              \
        GLOAD_LDS16(_ga,                  &As[nb_][w2 * 512 + lane * 8]);         \
        GLOAD_LDS16(_ga + (size_t)16 * K, &As[nb_][w2 * 512 + 512 + lane * 8]);   \
        GLOAD_LDS16(_gb,                  &Bs[nb_][w2 * 512 + lane * 8]);         \
        GLOAD_LDS16(_gb + (size_t)16 * K, &Bs[nb_][w2 * 512 + 512 + lane * 8]); } while (0)

    f32x4 acc[4][4];
    #pragma unroll
    for (int i = 0; i < 4; ++i)
        #pragma unroll
        for (int j = 0; j < 4; ++j) { f32x4 z = {0.f,0.f,0.f,0.f}; acc[i][j] = z; }

#define OCOMP(t) do {                                                             \
        const int b_ = (t) & 1;                                                   \
        bf16x8 af_[4], bf_[4];                                                    \
        _Pragma("unroll")                                                         \
        for (int i = 0; i < 4; ++i)                                               \
            af_[i] = *(const bf16x8*)(&As[b_][((wm2 * 4 + i) << 9) + rd_in]);     \
        _Pragma("unroll")                                                         \
        for (int j = 0; j < 4; ++j)                                               \
            bf_[j] = *(const bf16x8*)(&Bs[b_][((wn2 * 4 + j) << 9) + rd_in]);     \
        _Pragma("unroll")                                                         \
        for (int i = 0; i < 4; ++i)                                               \
            _Pragma("unroll")                                                     \
            for (int j = 0; j < 4; ++j)                                           \
                acc[i][j] = __builtin_amdgcn_mfma_f32_16x16x32_bf16(af_[i], bf_[j], acc[i][j], 0, 0, 0); } while (0)

    OSTAGE(0);
    VMCNT0();
    BAR();
    #pragma unroll 2
    for (int t = 0; t < NT - 1; ++t) {
        OSTAGE(t + 1);
        OCOMP(t);
        VMCNT0();
        BAR();
    }
    OCOMP(NT - 1);
#undef OSTAGE
#undef OCOMP

    #pragma unroll
    for (int i = 0; i < 4; ++i)
        #pragma unroll
        for (int j = 0; j < 4; ++j) {
            int col = bx * 128 + wn2 * 64 + j * 16 + l16;
            #pragma unroll
            for (int r = 0; r < 4; ++r) {
                int row = by * 128 + wm2 * 64 + i * 16 + quad * 4 + r;
                C[(size_t)row * HID + col] = acc[i][j][r];
            }
        }
}

// ------- q/k RMSNorm + partial RoPE, in place. grid = B*S blocks of 256. -------
__global__ __launch_bounds__(256) void norm_rope(unsigned short* __restrict__ qkv,
                                                 const int* __restrict__ positions,
                                                 const float* __restrict__ qw,
                                                 const float* __restrict__ kw)
{
    int bs = blockIdx.x;
    int s  = bs & (S_ - 1);
    int tid = threadIdx.x;
    int l16 = tid & 15;
    unsigned short* base = qkv + (size_t)bs * NKV;
    float pos = (float)positions[s];

    #pragma unroll
    for (int p = 0; p < 2; ++p) {
        int rr = p * 16 + (tid >> 4);   // 0..31
        int qk = rr >> 4;
        int h  = rr & 15;
        unsigned short* row = base + qk * HID + h * HD;
        const float* w = qk ? kw : qw;
        uint4 v = *(const uint4*)(row + l16 * 8);
        float x[8];
        x[0] = b2f(v.x); x[1] = b2f(v.x >> 16);
        x[2] = b2f(v.y); x[3] = b2f(v.y >> 16);
        x[4] = b2f(v.z); x[5] = b2f(v.z >> 16);
        x[6] = b2f(v.w); x[7] = b2f(v.w >> 16);
        float ss = 0.f;
        #pragma unroll
        for (int t = 0; t < 8; ++t) ss += x[t] * x[t];
        ss += __shfl_xor(ss, 1); ss += __shfl_xor(ss, 2);
        ss += __shfl_xor(ss, 4); ss += __shfl_xor(ss, 8);
        float inv = rsqrtf(ss * (1.0f / 128.0f) + 1e-6f);
        float n[8];
        #pragma unroll
        for (int t = 0; t < 8; ++t) n[t] = x[t] * inv * w[l16 * 8 + t];
        float pr[8];
        #pragma unroll
        for (int t = 0; t < 8; ++t) pr[t] = __shfl_xor(n[t], 4);   // dims +-32
        if (l16 < 8) {
            #pragma unroll
            for (int t = 0; t < 8; ++t) {
                int dim = l16 * 8 + t;
                int i = dim & 31;
                float ang = pos * exp2f(-(float)i * 0.4152410118609203f);
                float cs = cosf(ang), sn = sinf(ang);
                n[t] = (dim < 32) ? (n[t] * cs - pr[t] * sn) : (n[t] * cs + pr[t] * sn);
            }
        }
        uint4 o;
        o.x = f2b(n[0]) | (f2b(n[1]) << 16);
        o.y = f2b(n[2]) | (f2b(n[3]) << 16);
        o.z = f2b(n[4]) | (f2b(n[5]) << 16);
        o.w = f2b(n[6]) | (f2b(n[7]) << 16);
        *(uint4*)(row + l16 * 8) = o;
    }
}

// ============ pass 1: per-chunk KV outer product  Wt[e][d] = sum_j kdec_j V[j][e] K[j][d]
__global__ __launch_bounds__(256) void chunk_kv(const unsigned short* __restrict__ qkv,
                                                unsigned short* __restrict__ wbuf)
{
    __shared__ unsigned short kt[128 * 72];   // kt[d][j]
    __shared__ unsigned short vt[128 * 72];   // vt[e][j] * kdec[j]
    int bi = blockIdx.x;
    int c = bi & 31, bh = bi >> 5, h = bh & 15, b = bh >> 4;
    int tid = threadIdx.x;
    float slope = -exp2f(-0.5f * (float)(h + 1)) * (1.0f + 1e-5f);

    const unsigned short* kbase = qkv + ((size_t)(b * S_ + c * CHUNK_)) * NKV + HID + h * HD;
    const unsigned short* vbase = kbase + HID;

    for (int idx = tid; idx < 4096; idx += 256) {
        int j = idx >> 6, p = idx & 63;
        unsigned int ku = *(const unsigned int*)(kbase + (size_t)j * NKV + p * 2);
        kt[(2 * p) * 72 + j]     = (unsigned short)(ku & 0xffffu);
        kt[(2 * p + 1) * 72 + j] = (unsigned short)(ku >> 16);
        float kd = expf(slope * (float)(63 - j));
        unsigned int vu = *(const unsigned int*)(vbase + (size_t)j * NKV + p * 2);
        vt[(2 * p) * 72 + j]     = (unsigned short)f2b(b2f(vu) * kd);
        vt[(2 * p + 1) * 72 + j] = (unsigned short)f2b(b2f(vu >> 16) * kd);
    }
    __syncthreads();

    int lane = tid & 63, wave = tid >> 6;
    int wm = (wave >> 1) * 64;     // e
    int wn = (wave & 1) * 64;      // d
    int l16 = lane & 15, quad = lane >> 4;

    f32x4 acc[4][4];
    #pragma unroll
    for (int i = 0; i < 4; ++i)
        #pragma unroll
        for (int j = 0; j < 4; ++j) { f32x4 z = {0.f,0.f,0.f,0.f}; acc[i][j] = z; }

    #pragma unroll
    for (int ks = 0; ks < 64; ks += 32) {
        bf16x8 af[4], bf[4];
        #pragma unroll
        for (int t = 0; t < 4; ++t) {
            af[t] = *(const bf16x8*)((const bf16_t*)vt + (wm + t * 16 + l16) * 72 + ks + quad * 8);
            bf[t] = *(const bf16x8*)((const bf16_t*)kt + (wn + t * 16 + l16) * 72 + ks + quad * 8);
        }
        #pragma unroll
        for (int mt = 0; mt < 4; ++mt)
            #pragma unroll
            for (int nt = 0; nt < 4; ++nt)
                acc[mt][nt] = __builtin_amdgcn_mfma_f32_16x16x32_bf16(af[mt], bf[nt], acc[mt][nt], 0, 0, 0);
    }

    unsigned short* wp = wbuf + ((size_t)bi << 14);  // [e][d] 128x128
    #pragma unroll
    for (int mt = 0; mt < 4; ++mt)
        #pragma unroll
        for (int nt = 0; nt < 4; ++nt) {
            int dcol = wn + nt * 16 + l16;
            #pragma unroll
            for (int r = 0; r < 4; ++r) {
                int erow = wm + mt * 16 + quad * 4 + r;
                wp[(size_t)erow * 128 + dcol] = (unsigned short)f2b(acc[mt][nt][r]);
            }
        }
}

// ============ pass 2: sequential state scan (linear recurrence), 512 blocks
__global__ __launch_bounds__(256) void state_scan(const unsigned short* __restrict__ wbuf,
                                                  const float* __restrict__ rs0,
                                                  unsigned short* __restrict__ stbuf)
{
    int bi = blockIdx.x;
    int es = bi & 15, bh = bi >> 4, h = bh & 15, b = bh >> 4;
    int tid = threadIdx.x;
    float slope = -exp2f(-0.5f * (float)(h + 1)) * (1.0f + 1e-5f);
    float lam = expf(slope * 64.0f);

    int e  = es * 8 + (tid >> 5);
    int d0 = (tid & 31) * 4;

    float S[4];
    const float* rp = rs0 + ((size_t)(b * NH + h)) * HD * HD + e;   // rstate[b][h][d][e]
    #pragma unroll
    for (int t = 0; t < 4; ++t) S[t] = rp[(size_t)(d0 + t) * HD];

    size_t off = (size_t)e * 128 + d0;
    size_t base = (((size_t)bh * NC) << 14) + off;
    // depth-2 w prefetch: breaks the store->load->update serial chain
    uint2 w0 = *(const uint2*)(wbuf + base);
    uint2 w1 = *(const uint2*)(wbuf + base + (1 << 14));
    for (int c = 0; c < NC; ++c) {
        uint2 o;
        o.x = f2b(S[0]) | (f2b(S[1]) << 16);
        o.y = f2b(S[2]) | (f2b(S[3]) << 16);
        *(uint2*)(stbuf + base) = o;
        uint2 w2 = w1;
        if (c + 2 < NC) w2 = *(const uint2*)(wbuf + base + (2 << 14));
        S[0] = S[0] * lam + b2f(w0.x);
        S[1] = S[1] * lam + b2f(w0.x >> 16);
        S[2] = S[2] * lam + b2f(w0.y);
        S[3] = S[3] * lam + b2f(w0.y >> 16);
        w0 = w1; w1 = w2;
        base += (1 << 14);
    }
}

// ============ pass 3: per-chunk output  O = (mask.QK^T)@V + qdec*(Q@S_prev)
// v5: k-tile staged into LDS (was: per-frag global reads at per-lane stride
// NKV = 4096 scattered 16B transactions/block -> 4-8x cache-sector
// amplification). Stage is coalesced like q; frag reads pad-136 ~2-way.
__global__ __launch_bounds__(256) void chunk_out(const unsigned short* __restrict__ qkv,
                                                 const unsigned short* __restrict__ stbuf,
                                                 unsigned short* __restrict__ obuf)
{
    __shared__ unsigned short qs[64 * 136];   // q[i][d]
    __shared__ unsigned short kss[64 * 136];  // k[j][d]
    __shared__ unsigned short vt[128 * 72];   // v^T[e][j]
    __shared__ unsigned short sc[64 * 72];    // masked scores [i][j]

    int bi = blockIdx.x;
    int c = bi & 31, bh = bi >> 5, h = bh & 15, b = bh >> 4;
    int tid = threadIdx.x;
    float slope = -exp2f(-0.5f * (float)(h + 1)) * (1.0f + 1e-5f);

    int lane = tid & 63, wave = tid >> 6;
    int l16 = lane & 15, quad = lane >> 4;
    int wn3 = wave * 32;

    // ---- prefetch st B-frags into registers FIRST: HBM latency (~900cyc) hides
    //      behind staging + scores + intra phases.
    const unsigned short* stp = stbuf + (((size_t)bh * NC + c) << 14);
    bf16x8 bsf[4][2];
    #pragma unroll
    for (int ksp4 = 0; ksp4 < 4; ++ksp4)
        #pragma unroll
        for (int nt = 0; nt < 2; ++nt)
            bsf[ksp4][nt] = *(const bf16x8*)((const bf16_t*)stp +
                (size_t)(wn3 + nt * 16 + l16) * 128 + ksp4 * 32 + quad * 8);

    const unsigned short* qrow = qkv + ((size_t)(b * S_ + c * CHUNK_)) * NKV + h * HD;
    const unsigned short* krow = qrow + HID;
    // stage q and k (rows of 128, padded stride 136), coalesced uint4
    for (int idx = tid; idx < 1024; idx += 256) {
        int row = idx >> 4, c8 = (idx & 15) * 8;
        *(uint4*)(qs  + row * 136 + c8) = *(const uint4*)(qrow + (size_t)row * NKV + c8);
        *(uint4*)(kss + row * 136 + c8) = *(const uint4*)(krow + (size_t)row * NKV + c8);
    }
    // stage v transposed
    const unsigned short* vbase = qrow + 2 * HID;
    for (int idx = tid; idx < 4096; idx += 256) {
        int j = idx >> 6, p = idx & 63;
        unsigned int vu = *(const unsigned int*)(vbase + (size_t)j * NKV + p * 2);
        vt[(2 * p) * 72 + j]     = (unsigned short)(vu & 0xffffu);
        vt[(2 * p + 1) * 72 + j] = (unsigned short)(vu >> 16);
    }
    __syncthreads();

    // ---- scores: each wave computes rows [wave*16, +16) x all 64 j ----
    {
        f32x4 accS[4];
        #pragma unroll
        for (int t = 0; t < 4; ++t) { f32x4 z = {0.f,0.f,0.f,0.f}; accS[t] = z; }
        #pragma unroll
        for (int ksp = 0; ksp < 128; ksp += 32) {
            bf16x8 aq = *(const bf16x8*)((const bf16_t*)qs + (wave * 16 + l16) * 136 + ksp + quad * 8);
            #pragma unroll
            for (int nt = 0; nt < 4; ++nt) {
                bf16x8 bk = *(const bf16x8*)((const bf16_t*)kss + (nt * 16 + l16) * 136 + ksp + quad * 8);
                accS[nt] = __builtin_amdgcn_mfma_f32_16x16x32_bf16(aq, bk, accS[nt], 0, 0, 0);
            }
        }
        float ad[4];
        #pragma unroll
        for (int r = 0; r < 4; ++r) ad[r] = expf(slope * (float)(wave * 16 + quad * 4 + r));
        #pragma unroll
        for (int nt = 0; nt < 4; ++nt) {
            int j = nt * 16 + l16;
            float bd = expf(-slope * (float)j);
            #pragma unroll
            for (int r = 0; r < 4; ++r) {
                int i = wave * 16 + quad * 4 + r;
                float v = (i >= j) ? accS[nt][r] * ad[r] * bd : 0.0f;
                sc[i * 72 + j] = (unsigned short)f2b(v);
            }
        }
    }
    __syncthreads();

    f32x4 accI[4][2], accE[4][2];
    #pragma unroll
    for (int i = 0; i < 4; ++i)
        #pragma unroll
        for (int j = 0; j < 2; ++j) { f32x4 z = {0.f,0.f,0.f,0.f}; accI[i][j] = z; accE[i][j] = z; }

    // intra: K = 64 (j)
    #pragma unroll
    for (int ksp = 0; ksp < 64; ksp += 32) {
        bf16x8 as[4], bv[2];
        #pragma unroll
        for (int mt = 0; mt < 4; ++mt)
            as[mt] = *(const bf16x8*)((const bf16_t*)sc + (mt * 16 + l16) * 72 + ksp + quad * 8);
        #pragma unroll
        for (int nt = 0; nt < 2; ++nt)
            bv[nt] = *(const bf16x8*)((const bf16_t*)vt + (wn3 + nt * 16 + l16) * 72 + ksp + quad * 8);
        #pragma unroll
        for (int mt = 0; mt < 4; ++mt)
            #pragma unroll
            for (int nt = 0; nt < 2; ++nt)
                accI[mt][nt] = __builtin_amdgcn_mfma_f32_16x16x32_bf16(as[mt], bv[nt], accI[mt][nt], 0, 0, 0);
    }
    // inter: K = 128 (d), B-frags already in registers (bsf)
    #pragma unroll
    for (int ksp4 = 0; ksp4 < 4; ++ksp4) {
        bf16x8 aq[4];
        #pragma unroll
        for (int mt = 0; mt < 4; ++mt)
            aq[mt] = *(const bf16x8*)((const bf16_t*)qs + (mt * 16 + l16) * 136 + ksp4 * 32 + quad * 8);
        #pragma unroll
        for (int mt = 0; mt < 4; ++mt)
            #pragma unroll
            for (int nt = 0; nt < 2; ++nt)
                accE[mt][nt] = __builtin_amdgcn_mfma_f32_16x16x32_bf16(aq[mt], bsf[ksp4][nt], accE[mt][nt], 0, 0, 0);
    }

    // epilogue: O = accI + qdec[i]*accE, bf16 store
    #pragma unroll
    for (int mt = 0; mt < 4; ++mt) {
        #pragma unroll
        for (int r = 0; r < 4; ++r) {
            int i = mt * 16 + quad * 4 + r;
            float qd = expf(slope * (float)(i + 1));
            int orow = b * S_ + c * CHUNK_ + i;
            #pragma unroll
            for (int nt = 0; nt < 2; ++nt) {
                int col = h * HD + wn3 + nt * 16 + l16;
                float o = accI[mt][nt][r] + qd * accE[mt][nt][r];
                obuf[(size_t)orow * 2048 + col] = (unsigned short)f2b(o);
            }
        }
    }
}

// ------- group RMSNorm + sigmoid gate: read o bf16 + gate bf16, write bf16 -------
__global__ __launch_bounds__(256) void gnorm_gate(const unsigned short* __restrict__ o,
                                                  unsigned short* __restrict__ gate,
                                                  const float* __restrict__ gw)
{
    int row = blockIdx.x >> 3;
    int g   = blockIdx.x & 7;
    int col = g * 256 + threadIdx.x;
    size_t idx = (size_t)row * 2048 + col;
    float ov = b2f(o[idx]);
    float ss = ov * ov;
    #pragma unroll
    for (int off = 32; off > 0; off >>= 1) ss += __shfl_xor(ss, off);
    __shared__ float part[4];
    if ((threadIdx.x & 63) == 0) part[threadIdx.x >> 6] = ss;
    __syncthreads();
    float tot = part[0] + part[1] + part[2] + part[3];
    float inv = rsqrtf(tot * (1.0f / 256.0f) + 1e-6f);
    float gv = b2f(gate[idx]);
    float sig = 1.0f / (1.0f + expf(-gv));
    gate[idx] = (unsigned short)f2b(ov * inv * gw[col] * sig);
}

// ---------------- launch ----------------
extern "C" void kernel_launch(void* const* d_in, const int* in_sizes, int n_in,
                              void* d_out, int out_size, void* d_ws, size_t ws_size,
                              hipStream_t stream) {
    const int*   positions = (const int*)d_in[0];
    const float* hidden    = (const float*)d_in[1];
    const float* rstate    = (const float*)d_in[2];
    const float* w_qkv     = (const float*)d_in[3];
    const float* w_g       = (const float*)d_in[4];
    const float* w_dense   = (const float*)d_in[5];
    const float* q_norm_w  = (const float*)d_in[6];
    const float* k_norm_w  = (const float*)d_in[7];
    const float* g_norm_w  = (const float*)d_in[8];
    float* out = (float*)d_out;

    const int MR = B_ * S_;  // 4096

    // ---- ws layout (total 159,383,552 B — unchanged) ----
    char* w = (char*)d_ws;
    unsigned short* qkv  = (unsigned short*)w;            w += (size_t)MR * NKV * 2;     // 50.3 MB
    unsigned short* gbuf = (unsigned short*)w;            w += (size_t)MR * 2048 * 2;    // 16.8 MB
    unsigned short* wdT  = (unsigned short*)w;            w += (size_t)HID * HID * 2;    // 8.4 MB
    char* regionA = w;                                    w += (size_t)MR * HID * 2 + (size_t)8192 * HID * 2; // 50.3 MB
    char* regionB = w;                                    // 33.6 MB
    unsigned short* hbf   = (unsigned short*)regionA;                                 // 16.8 MB
    unsigned short* btQG  = (unsigned short*)(regionA + (size_t)MR * HID * 2);        // [8192][2048] 33.5 MB
    unsigned short* wqT   = btQG;                                                     // rows 0..6143
    unsigned short* wgT   = btQG + (size_t)NKV * HID;                                 // rows 6144..8191
    unsigned short* stbuf = (unsigned short*)regionA;     // 32 MB, after GEMMs
    unsigned short* wbuf  = (unsigned short*)regionB;     // 32 MB
    unsigned short* obuf  = (unsigned short*)regionB;     // 16.8 MB, after pass2

    // ---- conversions ----
    cvt_bf16<<<dim3((MR * HID / 8 + 255) / 256), dim3(256), 0, stream>>>(hidden, hbf, MR * HID / 8);
    transpose_cvt<<<dim3((HID / 32) * (NKV / 32)), dim3(256), 0, stream>>>(w_qkv, wqT, HID, NKV);
    transpose_cvt<<<dim3((HID / 32) * (HID / 32)), dim3(256), 0, stream>>>(w_g, wgT, HID, HID);
    transpose_cvt<<<dim3((HID / 32) * (HID / 32)), dim3(256), 0, stream>>>(w_dense, wdT, HID, HID);

    // ---- fused qkv+gate projection: 256^2 barrier-light (512 wg x 512 thr) ----
    gemm_qg_256<<<dim3(512), dim3(512), 0, stream>>>(
        (const bf16_t*)hbf, (const bf16_t*)btQG, qkv, gbuf);
    // ---- q/k norm + rope (in place) ----
    norm_rope<<<dim3(B_ * S_), dim3(256), 0, stream>>>(qkv, positions, q_norm_w, k_norm_w);

    // ---- attention: 3-pass chunked scan ----
    chunk_kv<<<dim3(B_ * NH * NC), dim3(256), 0, stream>>>(qkv, wbuf);
    state_scan<<<dim3(B_ * NH * 16), dim3(256), 0, stream>>>(wbuf, rstate, stbuf);
    chunk_out<<<dim3(B_ * NH * NC), dim3(256), 0, stream>>>(qkv, stbuf, obuf);

    // ---- group norm + gate ----
    gnorm_gate<<<dim3(MR * GROUPS_), dim3(256), 0, stream>>>(obuf, gbuf, g_norm_w);
    // ---- output projection (fp32 out), barrier-light 128^2 ----
    gemm_out_128<<<dim3(512), dim3(256), 0, stream>>>(
        (const bf16_t*)gbuf, (const bf16_t*)wdT, out);
}